// Round 1
// baseline (686.614 us; speedup 1.0000x reference)
//
#include <hip/hip_runtime.h>
#include <hip/hip_bf16.h>
#include <math.h>

#define B_   4
#define L_   2048
#define E_   1024
#define H_   16
#define DH_  64
#define HID_ 1024
#define ROWS (B_*L_)      // 8192
#define NCH  16
#define CLEN (L_/NCH)     // 128

typedef __attribute__((ext_vector_type(8))) short short8;
typedef __attribute__((ext_vector_type(4))) float f32x4;

__device__ __forceinline__ unsigned short f2bf(float f) {
  union { float f; unsigned int i; } v; v.f = f;
  unsigned int r = v.i + 0x7fffu + ((v.i >> 16) & 1u);
  return (unsigned short)(r >> 16);
}

__device__ __forceinline__ void gload16(const unsigned short* g, unsigned short* l) {
  __builtin_amdgcn_global_load_lds((const __attribute__((address_space(1))) void*)g,
                                   (__attribute__((address_space(3))) void*)l, 16, 0, 0);
}

// ---------------- elementwise cast f32 -> bf16 (4/thread) ----------------
__global__ void cast_f32_bf16(const float* __restrict__ src, unsigned short* __restrict__ dst, int n) {
  int i = (blockIdx.x * 256 + threadIdx.x) * 4;
  if (i < n) {
    float4 v = *(const float4*)(src + i);
    ushort4 o;
    o.x = f2bf(v.x); o.y = f2bf(v.y); o.z = f2bf(v.z); o.w = f2bf(v.w);
    *(ushort4*)(dst + i) = o;
  }
}

// ---------------- tiled transpose + cast: dst[(dstBase+z*C+c)*R + r] = src[z][r][c] ----------------
__global__ void transpose_cast(const float* __restrict__ src, unsigned short* __restrict__ dst,
                               int R, int C, int dstBase) {
  __shared__ float tile[32][33];
  src += (size_t)blockIdx.z * R * C;
  int dstRow0 = dstBase + blockIdx.z * C;
  int rb = blockIdx.x * 32, cb = blockIdx.y * 32;
  for (int i = threadIdx.y; i < 32; i += 8)
    tile[i][threadIdx.x] = src[(size_t)(rb + i) * C + cb + threadIdx.x];
  __syncthreads();
  for (int i = threadIdx.y; i < 32; i += 8)
    dst[(size_t)(dstRow0 + cb + i) * R + rb + threadIdx.x] = f2bf(tile[threadIdx.x][i]);
}

// ---------------- concat bias [ba|bb|bD] ----------------
__global__ void build_bias(const float* __restrict__ ba, const float* __restrict__ bb,
                           const float* __restrict__ bD, float* __restrict__ bias) {
  int i = blockIdx.x * 256 + threadIdx.x;   // < 3072
  const float* src = (i < 1024) ? ba : ((i < 2048) ? bb : bD);
  bias[i] = src[i & 1023];
}

// ---------------- bf16 MFMA GEMM: C[M,N] = A[M,K] * Bt[N,K]^T + bias, fused epilogue ----------------
#define EPI_GATES 0   // f32 out; tanh on cols < 1024
#define EPI_GELU  1   // bf16 out; exact gelu
#define EPI_RES   2   // bf16 out; + res (f32)
#define EPI_OUT   3   // f32 out

template<int EPI>
__global__ __launch_bounds__(256)
void gemm_bt(const unsigned short* __restrict__ A, const unsigned short* __restrict__ Bt,
             const float* __restrict__ bias, const float* __restrict__ res,
             void* __restrict__ out, int M, int N, int K) {
  __shared__ unsigned short lA[128 * 32];
  __shared__ unsigned short lB[128 * 32];
  const int tid = threadIdx.x;
  const int w = tid >> 6, l = tid & 63;
  const int row0 = blockIdx.y * 128, col0 = blockIdx.x * 128;

  // staging: per issue i in {0,1}: seg = i*4+w; lane l covers elems seg*512 + l*8
  const int rA0 = w * 16 + (l >> 2);
  const int rA1 = (4 + w) * 16 + (l >> 2);
  const int koff = (l & 3) * 8;
  const unsigned short* gA0 = A + (size_t)(row0 + rA0) * K + koff;
  const unsigned short* gA1 = A + (size_t)(row0 + rA1) * K + koff;
  const unsigned short* gB0 = Bt + (size_t)(col0 + rA0) * K + koff;
  const unsigned short* gB1 = Bt + (size_t)(col0 + rA1) * K + koff;
  unsigned short* lA0 = lA + w * 512;        // wave-uniform LDS bases
  unsigned short* lA1 = lA + (4 + w) * 512;
  unsigned short* lB0 = lB + w * 512;
  unsigned short* lB1 = lB + (4 + w) * 512;

  const int wr = (w >> 1) * 64, wc = (w & 1) * 64;
  f32x4 acc[4][4];
  #pragma unroll
  for (int m = 0; m < 4; m++)
    #pragma unroll
    for (int n = 0; n < 4; n++) acc[m][n] = (f32x4){0.f, 0.f, 0.f, 0.f};

  const int arow = wr + (l & 15);
  const int brow = wc + (l & 15);
  const int kg = (l >> 4) * 8;

  for (int kt = 0; kt < K; kt += 32) {
    __syncthreads();                       // prev compute done before overwrite
    gload16(gA0 + kt, lA0);
    gload16(gA1 + kt, lA1);
    gload16(gB0 + kt, lB0);
    gload16(gB1 + kt, lB1);
    __syncthreads();                       // staging drained (vmcnt before barrier)
    short8 af[4], bfr[4];
    #pragma unroll
    for (int m = 0; m < 4; m++) af[m]  = *(const short8*)(lA + (arow + m * 16) * 32 + kg);
    #pragma unroll
    for (int n = 0; n < 4; n++) bfr[n] = *(const short8*)(lB + (brow + n * 16) * 32 + kg);
    #pragma unroll
    for (int m = 0; m < 4; m++)
      #pragma unroll
      for (int n = 0; n < 4; n++)
        acc[m][n] = __builtin_amdgcn_mfma_f32_16x16x32_bf16(af[m], bfr[n], acc[m][n], 0, 0, 0);
  }

  const int er = row0 + wr + ((l >> 4) << 2);
  const int ec = col0 + wc + (l & 15);
  #pragma unroll
  for (int m = 0; m < 4; m++) {
    #pragma unroll
    for (int n = 0; n < 4; n++) {
      #pragma unroll
      for (int j = 0; j < 4; j++) {
        int rr = er + m * 16 + j;
        int cc = ec + n * 16;
        float x = acc[m][n][j] + bias[cc];
        if (EPI == EPI_GATES) {
          if (cc < HID_) x = tanhf(x);
          ((float*)out)[(size_t)rr * N + cc] = x;
        } else if (EPI == EPI_GELU) {
          x = 0.5f * x * (1.f + erff(x * 0.70710678118654752f));
          ((unsigned short*)out)[(size_t)rr * N + cc] = f2bf(x);
        } else if (EPI == EPI_RES) {
          x += res[(size_t)rr * N + cc];
          ((unsigned short*)out)[(size_t)rr * N + cc] = f2bf(x);
        } else {
          ((float*)out)[(size_t)rr * N + cc] = x;
        }
      }
    }
  }
}

// ---------------- chunked affine scan h_t = a_t*h_{t-1} + b_t ----------------
// abd layout: [ROWS][3072] f32; a = cols 0..1023 (tanh'd), b = 1024..2047, d = 2048..3071
__global__ void scan_p1(const float* __restrict__ abd, float* __restrict__ aggA, float* __restrict__ aggB) {
  int id = blockIdx.x * 256 + threadIdx.x;          // B*NCH*1024 = 65536
  int c = id & 1023;
  int chunk = (id >> 10) & (NCH - 1);
  int bb = id >> 14;
  const float* base = abd + (size_t)(bb * L_ + chunk * CLEN) * 3072;
  float Aa = 1.f, Bv = 0.f;
  #pragma unroll 4
  for (int t = 0; t < CLEN; ++t) {
    float a = base[(size_t)t * 3072 + c];
    float b = base[(size_t)t * 3072 + 1024 + c];
    Aa *= a;
    Bv = a * Bv + b;
  }
  int o = (chunk * B_ + bb) * 1024 + c;
  aggA[o] = Aa; aggB[o] = Bv;
}

__global__ void scan_p2(const float* __restrict__ aggA, const float* __restrict__ aggB,
                        float* __restrict__ hinit) {
  int id = blockIdx.x * 256 + threadIdx.x;          // 4096 = bb*1024 + c
  float hc = 0.f;
  for (int ch = 0; ch < NCH; ++ch) {
    int o = ch * 4096 + id;
    hinit[o] = hc;
    hc = aggA[o] * hc + aggB[o];
  }
}

__global__ void scan_p3(const float* __restrict__ abd, const float* __restrict__ hinit,
                        float* __restrict__ hbuf) {
  int id = blockIdx.x * 256 + threadIdx.x;
  int c = id & 1023;
  int chunk = (id >> 10) & (NCH - 1);
  int bb = id >> 14;
  const float* base = abd + (size_t)(bb * L_ + chunk * CLEN) * 3072;
  float* hb = hbuf + (size_t)(bb * L_ + chunk * CLEN) * 1024;
  float h = hinit[chunk * 4096 + bb * 1024 + c];
  #pragma unroll 4
  for (int t = 0; t < CLEN; ++t) {
    float a = base[(size_t)t * 3072 + c];
    float b = base[(size_t)t * 3072 + 1024 + c];
    h = a * h + b;
    hb[(size_t)t * 1024 + c] = h;
  }
}

// ---------------- head mix: z = (h @ WC + bC) * d ----------------
__global__ void head_out(const float* __restrict__ hbuf, const float* __restrict__ WC,
                         const float* __restrict__ bC, const float* __restrict__ abd,
                         float* __restrict__ z) {
  int id = blockIdx.x * 256 + threadIdx.x;
  int col = id & 1023;
  int row = id >> 10;
  int h = col >> 6, f = col & 63;
  const float* hr = hbuf + (size_t)row * 1024 + h * 64;
  const float* wc = WC + (size_t)h * 4096 + f;
  float s = bC[col];
  #pragma unroll 8
  for (int d = 0; d < 64; ++d) s += hr[d] * wc[(size_t)d * 64];
  float dg = abd[(size_t)row * 3072 + 2048 + col];
  z[(size_t)row * 1024 + col] = s * dg;
}

// ---------------- u = z + LN(z); outputs f32 + bf16 ----------------
__global__ __launch_bounds__(256)
void ln_res(const float* __restrict__ z, const float* __restrict__ lg, const float* __restrict__ lb,
            float* __restrict__ u32, unsigned short* __restrict__ u16) {
  int row = blockIdx.x;
  int t = threadIdx.x;
  const float4 zv = *(const float4*)(z + (size_t)row * 1024 + t * 4);
  float s = zv.x + zv.y + zv.z + zv.w;
  float sq = zv.x * zv.x + zv.y * zv.y + zv.z * zv.z + zv.w * zv.w;
  #pragma unroll
  for (int o = 32; o > 0; o >>= 1) { s += __shfl_down(s, o); sq += __shfl_down(sq, o); }
  __shared__ float ps[4], pq[4];
  if ((t & 63) == 0) { ps[t >> 6] = s; pq[t >> 6] = sq; }
  __syncthreads();
  s = ps[0] + ps[1] + ps[2] + ps[3];
  sq = pq[0] + pq[1] + pq[2] + pq[3];
  float mu = s * (1.f / 1024.f);
  float var = sq * (1.f / 1024.f) - mu * mu;
  float rs = rsqrtf(var + 1e-5f);
  const float4 gv = *(const float4*)(lg + t * 4);
  const float4 bv = *(const float4*)(lb + t * 4);
  float4 o;
  o.x = zv.x + (zv.x - mu) * rs * gv.x + bv.x;
  o.y = zv.y + (zv.y - mu) * rs * gv.y + bv.y;
  o.z = zv.z + (zv.z - mu) * rs * gv.z + bv.z;
  o.w = zv.w + (zv.w - mu) * rs * gv.w + bv.w;
  *(float4*)(u32 + (size_t)row * 1024 + t * 4) = o;
  ushort4 ob; ob.x = f2bf(o.x); ob.y = f2bf(o.y); ob.z = f2bf(o.z); ob.w = f2bf(o.w);
  *(ushort4*)(u16 + (size_t)row * 1024 + t * 4) = ob;
}

extern "C" void kernel_launch(void* const* d_in, const int* in_sizes, int n_in,
                              void* d_out, int out_size, void* d_ws, size_t ws_size,
                              hipStream_t stream) {
  const float* emb    = (const float*)d_in[0];
  const float* Wa     = (const float*)d_in[1];
  const float* ba     = (const float*)d_in[2];
  const float* Wb     = (const float*)d_in[3];
  const float* bb     = (const float*)d_in[4];
  const float* WD     = (const float*)d_in[5];
  const float* bD     = (const float*)d_in[6];
  const float* WC     = (const float*)d_in[7];
  const float* bC     = (const float*)d_in[8];
  const float* ffn1_w = (const float*)d_in[9];
  const float* ffn1_b = (const float*)d_in[10];
  const float* ffn2_w = (const float*)d_in[11];
  const float* ffn2_b = (const float*)d_in[12];
  const float* proj_w = (const float*)d_in[13];
  const float* proj_b = (const float*)d_in[14];
  const float* ln_g   = (const float*)d_in[15];
  const float* ln_b   = (const float*)d_in[16];

  char* p = (char*)d_ws;
  auto alloc = [&](size_t bytes) { char* r = p; p += (bytes + 255) & ~(size_t)255; return (void*)r; };

  float* abd   = (float*)alloc((size_t)ROWS * 3072 * 4);    // a|b|d pre-activations / gates
  float* hbuf  = (float*)alloc((size_t)ROWS * 1024 * 4);    // scan output h
  float* zbuf  = (float*)alloc((size_t)ROWS * 1024 * 4);    // head output z
  float* u32   = (float*)alloc((size_t)ROWS * 1024 * 4);    // u f32 (residual)
  unsigned short* u16  = (unsigned short*)alloc((size_t)ROWS * 1024 * 2);
  unsigned short* embb = (unsigned short*)alloc((size_t)ROWS * 1024 * 2);
  unsigned short* wcat = (unsigned short*)alloc((size_t)3072 * 1024 * 2);
  unsigned short* f1t  = (unsigned short*)alloc((size_t)4096 * 1024 * 2);
  unsigned short* f2t  = (unsigned short*)alloc((size_t)4096 * 1024 * 2);
  unsigned short* pjt  = (unsigned short*)alloc((size_t)1024 * 1024 * 2);
  float* biascat = (float*)alloc(3072 * 4);
  float* aggA  = (float*)alloc(65536 * 4);
  float* aggB  = (float*)alloc(65536 * 4);
  float* hinit = (float*)alloc(65536 * 4);
  // aliased (disjoint lifetimes):
  unsigned short* gbuf = (unsigned short*)hbuf;   // [ROWS][4096] bf16 spans hbuf+zbuf (both dead by ffn1)
  unsigned short* vbuf = (unsigned short*)abd;    // [ROWS][1024] bf16 (abd dead after head_out)

  dim3 tb(32, 8);
  cast_f32_bf16<<<ROWS * 1024 / 1024, 256, 0, stream>>>(emb, embb, ROWS * 1024);
  build_bias<<<12, 256, 0, stream>>>(ba, bb, bD, biascat);
  transpose_cast<<<dim3(E_ / 32, DH_ / 32, H_), tb, 0, stream>>>(Wa, wcat, E_, DH_, 0);
  transpose_cast<<<dim3(E_ / 32, DH_ / 32, H_), tb, 0, stream>>>(Wb, wcat, E_, DH_, 1024);
  transpose_cast<<<dim3(E_ / 32, DH_ / 32, H_), tb, 0, stream>>>(WD, wcat, E_, DH_, 2048);
  transpose_cast<<<dim3(1024 / 32, 4096 / 32, 1), tb, 0, stream>>>(ffn1_w, f1t, 1024, 4096, 0);
  transpose_cast<<<dim3(4096 / 32, 1024 / 32, 1), tb, 0, stream>>>(ffn2_w, f2t, 4096, 1024, 0);
  transpose_cast<<<dim3(1024 / 32, 1024 / 32, 1), tb, 0, stream>>>(proj_w, pjt, 1024, 1024, 0);

  // G1: [8192,1024] x [1024,3072] -> abd (bias + tanh on a-cols)
  gemm_bt<EPI_GATES><<<dim3(3072 / 128, ROWS / 128), 256, 0, stream>>>(
      embb, wcat, biascat, nullptr, abd, ROWS, 3072, 1024);

  scan_p1<<<65536 / 256, 256, 0, stream>>>(abd, aggA, aggB);
  scan_p2<<<4096 / 256, 256, 0, stream>>>(aggA, aggB, hinit);
  scan_p3<<<65536 / 256, 256, 0, stream>>>(abd, hinit, hbuf);

  head_out<<<ROWS * 1024 / 256, 256, 0, stream>>>(hbuf, WC, bC, abd, zbuf);
  ln_res<<<ROWS, 256, 0, stream>>>(zbuf, ln_g, ln_b, u32, u16);

  // FFN1: [8192,1024] x [1024,4096] -> gelu -> gbuf (bf16)
  gemm_bt<EPI_GELU><<<dim3(4096 / 128, ROWS / 128), 256, 0, stream>>>(
      u16, f1t, ffn1_b, nullptr, gbuf, ROWS, 4096, 1024);
  // FFN2: [8192,4096] x [4096,1024] + u -> vbuf (bf16)
  gemm_bt<EPI_RES><<<dim3(1024 / 128, ROWS / 128), 256, 0, stream>>>(
      gbuf, f2t, ffn2_b, u32, vbuf, ROWS, 1024, 4096);
  // proj: [8192,1024] x [1024,1024] -> d_out (f32)
  gemm_bt<EPI_OUT><<<dim3(1024 / 128, ROWS / 128), 256, 0, stream>>>(
      vbuf, pjt, proj_b, nullptr, (float*)d_out, ROWS, 1024, 1024);
}

// Round 2
// 605.151 us; speedup vs baseline: 1.1346x; 1.1346x over previous
//
#include <hip/hip_runtime.h>
#include <hip/hip_bf16.h>
#include <math.h>

#define B_   4
#define L_   2048
#define E_   1024
#define H_   16
#define DH_  64
#define HID_ 1024
#define ROWS (B_*L_)      // 8192
#define NCH  16
#define CLEN (L_/NCH)     // 128

typedef __attribute__((ext_vector_type(8))) short short8;
typedef __attribute__((ext_vector_type(4))) float f32x4;

__device__ __forceinline__ unsigned short f2bf(float f) {
  union { float f; unsigned int i; } v; v.f = f;
  unsigned int r = v.i + 0x7fffu + ((v.i >> 16) & 1u);
  return (unsigned short)(r >> 16);
}

__device__ __forceinline__ void gload16(const unsigned short* g, unsigned short* l) {
  __builtin_amdgcn_global_load_lds((const __attribute__((address_space(1))) void*)g,
                                   (__attribute__((address_space(3))) void*)l, 16, 0, 0);
}

// ---------------- elementwise cast f32 -> bf16 (4/thread) ----------------
__global__ void cast_f32_bf16(const float* __restrict__ src, unsigned short* __restrict__ dst, int n) {
  int i = (blockIdx.x * 256 + threadIdx.x) * 4;
  if (i < n) {
    float4 v = *(const float4*)(src + i);
    ushort4 o;
    o.x = f2bf(v.x); o.y = f2bf(v.y); o.z = f2bf(v.z); o.w = f2bf(v.w);
    *(ushort4*)(dst + i) = o;
  }
}

// ---------------- tiled transpose + cast: dst[(dstBase+z*C+c)*R + r] = src[z][r][c] ----------------
__global__ void transpose_cast(const float* __restrict__ src, unsigned short* __restrict__ dst,
                               int R, int C, int dstBase) {
  __shared__ float tile[32][33];
  src += (size_t)blockIdx.z * R * C;
  int dstRow0 = dstBase + blockIdx.z * C;
  int rb = blockIdx.x * 32, cb = blockIdx.y * 32;
  for (int i = threadIdx.y; i < 32; i += 8)
    tile[i][threadIdx.x] = src[(size_t)(rb + i) * C + cb + threadIdx.x];
  __syncthreads();
  for (int i = threadIdx.y; i < 32; i += 8)
    dst[(size_t)(dstRow0 + cb + i) * R + rb + threadIdx.x] = f2bf(tile[threadIdx.x][i]);
}

// ---------------- concat bias [ba|bb|bD] ----------------
__global__ void build_bias(const float* __restrict__ ba, const float* __restrict__ bb,
                           const float* __restrict__ bD, float* __restrict__ bias) {
  int i = blockIdx.x * 256 + threadIdx.x;   // < 3072
  const float* src = (i < 1024) ? ba : ((i < 2048) ? bb : bD);
  bias[i] = src[i & 1023];
}

// ---------------- block-diag WC^T (bf16): dst[col][k] = (col/64==k/64) ? WC[h][k%64][col%64] : 0
__global__ void build_wcblk(const float* __restrict__ WC, unsigned short* __restrict__ dst) {
  int i = blockIdx.x * 256 + threadIdx.x;   // over 1024*1024
  int col = i >> 10, k = i & 1023;
  int hc = col >> 6, hk = k >> 6;
  float v = (hc == hk) ? WC[(size_t)hc * 4096 + (k & 63) * 64 + (col & 63)] : 0.f;
  dst[i] = f2bf(v);
}

// ---------------- shared fused epilogues ----------------
#define EPI_GATES 0   // f32 out; tanh on cols < 1024
#define EPI_GELU  1   // bf16 out; exact gelu
#define EPI_RES   2   // bf16 out; + aux (f32 residual, stride N)
#define EPI_OUT   3   // f32 out
#define EPI_HEAD  4   // f32 out; (acc+bias)*aux  (aux stride 3072)

template<int EPI>
__device__ __forceinline__ void epi_store(float xa, int rr, int cc, int N,
                                          const float* __restrict__ bias,
                                          const float* __restrict__ aux,
                                          void* __restrict__ out) {
  float x = xa + bias[cc];
  if (EPI == EPI_GATES) {
    if (cc < HID_) x = tanhf(x);
    ((float*)out)[(size_t)rr * N + cc] = x;
  } else if (EPI == EPI_GELU) {
    x = 0.5f * x * (1.f + erff(x * 0.70710678118654752f));
    ((unsigned short*)out)[(size_t)rr * N + cc] = f2bf(x);
  } else if (EPI == EPI_RES) {
    x += aux[(size_t)rr * N + cc];
    ((unsigned short*)out)[(size_t)rr * N + cc] = f2bf(x);
  } else if (EPI == EPI_HEAD) {
    x *= aux[(size_t)rr * 3072 + cc];
    ((float*)out)[(size_t)rr * N + cc] = x;
  } else {
    ((float*)out)[(size_t)rr * N + cc] = x;
  }
}

// ---------------- 128x128 m97-structure GEMM (known-good): C = A[M,K]*Bt[N,K]^T ----------------
template<int EPI>
__global__ __launch_bounds__(256)
void gemm_bt(const unsigned short* __restrict__ A, const unsigned short* __restrict__ Bt,
             const float* __restrict__ bias, const float* __restrict__ aux,
             void* __restrict__ out, int M, int N, int K) {
  __shared__ unsigned short lA[128 * 32];
  __shared__ unsigned short lB[128 * 32];
  const int tid = threadIdx.x;
  const int w = tid >> 6, l = tid & 63;
  const int row0 = blockIdx.y * 128, col0 = blockIdx.x * 128;

  const int rA0 = w * 16 + (l >> 2);
  const int rA1 = (4 + w) * 16 + (l >> 2);
  const int koff = (l & 3) * 8;
  const unsigned short* gA0 = A + (size_t)(row0 + rA0) * K + koff;
  const unsigned short* gA1 = A + (size_t)(row0 + rA1) * K + koff;
  const unsigned short* gB0 = Bt + (size_t)(col0 + rA0) * K + koff;
  const unsigned short* gB1 = Bt + (size_t)(col0 + rA1) * K + koff;
  unsigned short* lA0 = lA + w * 512;
  unsigned short* lA1 = lA + (4 + w) * 512;
  unsigned short* lB0 = lB + w * 512;
  unsigned short* lB1 = lB + (4 + w) * 512;

  const int wr = (w >> 1) * 64, wc = (w & 1) * 64;
  f32x4 acc[4][4];
  #pragma unroll
  for (int m = 0; m < 4; m++)
    #pragma unroll
    for (int n = 0; n < 4; n++) acc[m][n] = (f32x4){0.f, 0.f, 0.f, 0.f};

  const int arow = wr + (l & 15);
  const int brow = wc + (l & 15);
  const int kg = (l >> 4) * 8;

  for (int kt = 0; kt < K; kt += 32) {
    __syncthreads();
    gload16(gA0 + kt, lA0);
    gload16(gA1 + kt, lA1);
    gload16(gB0 + kt, lB0);
    gload16(gB1 + kt, lB1);
    __syncthreads();
    short8 af[4], bfr[4];
    #pragma unroll
    for (int m = 0; m < 4; m++) af[m]  = *(const short8*)(lA + (arow + m * 16) * 32 + kg);
    #pragma unroll
    for (int n = 0; n < 4; n++) bfr[n] = *(const short8*)(lB + (brow + n * 16) * 32 + kg);
    #pragma unroll
    for (int m = 0; m < 4; m++)
      #pragma unroll
      for (int n = 0; n < 4; n++)
        acc[m][n] = __builtin_amdgcn_mfma_f32_16x16x32_bf16(af[m], bfr[n], acc[m][n], 0, 0, 0);
  }

  const int er = row0 + wr + ((l >> 4) << 2);
  const int ec = col0 + wc + (l & 15);
  #pragma unroll
  for (int m = 0; m < 4; m++)
    #pragma unroll
    for (int n = 0; n < 4; n++)
      #pragma unroll
      for (int j = 0; j < 4; j++)
        epi_store<EPI>(acc[m][n][j], er + m * 16 + j, ec + n * 16, N, bias, aux, out);
}

// ---------------- 256x256 8-phase GEMM (T2 swizzle + T3/T4 counted vmcnt + T5 setprio) ----------
// Requires M%256==0, N%256==0, K%128==0.
template<int EPI>
__global__ __launch_bounds__(512, 2)
void gemm256(const unsigned short* __restrict__ A, const unsigned short* __restrict__ Bt,
             const float* __restrict__ bias, const float* __restrict__ aux,
             void* __restrict__ out, int M, int N, int K) {
  // lds[buf][mat][256 rows][64 k] bf16 ; 128 KiB total
  __shared__ unsigned short lds[2][2][256 * 64];
  const int tid = threadIdx.x;
  const int w = tid >> 6, l = tid & 63;
  const int wm = w >> 2, wn = w & 3;          // 2 (M) x 4 (N) waves
  const int row0 = blockIdx.y * 256, col0 = blockIdx.x * 256;
  const int lr = l & 15, kg = (l >> 4) << 3;
  const int wmb = wm * 128, wnb = wn * 64;
  const int T = K >> 6, nIter = T >> 1;

  // staging geometry: half-tile = 128 rows x 64 k = 16KB = 512thr x 2 x 16B.
  // LDS dest linear (wave-uniform base + lane*16); global source k pre-swizzled
  // so that swizzled reads (byte ^ ((row&7)<<4)) hit the right element.
  const int srow = w * 8 + (l >> 3);                 // local row, load j=0
  const int kswz = (((l & 7) ^ (l >> 3)) << 3);      // k element offset (pre-swizzled)

  f32x4 acc[8][4];
  #pragma unroll
  for (int m = 0; m < 8; m++)
    #pragma unroll
    for (int n = 0; n < 4; n++) acc[m][n] = (f32x4){0.f, 0.f, 0.f, 0.f};

  short8 a[4][2], b0[2][2], b1[2][2];

  auto stA = [&](int buf, int hh, int kt) {
    const unsigned short* g = A + (size_t)(row0 + hh * 128 + srow) * K + kt * 64 + kswz;
    unsigned short* d = &lds[buf][0][hh * 8192 + w * 512];
    gload16(g, d);
    gload16(g + (size_t)64 * K, d + 4096);
  };
  auto stB = [&](int buf, int hh, int kt) {
    const unsigned short* g = Bt + (size_t)(col0 + hh * 128 + srow) * K + kt * 64 + kswz;
    unsigned short* d = &lds[buf][1][hh * 8192 + w * 512];
    gload16(g, d);
    gload16(g + (size_t)64 * K, d + 4096);
  };

#define RD_A(LP, mh) { _Pragma("unroll") for (int mf = 0; mf < 4; ++mf) { _Pragma("unroll") for (int ks = 0; ks < 2; ++ks) { \
      int r = wmb + (mh) * 64 + mf * 16 + lr; int k = ks * 32 + kg; \
      a[mf][ks] = *(const short8*)((LP) + r * 64 + (k ^ ((r & 7) << 3))); } } }
#define RD_B(dst, LP, nh) { _Pragma("unroll") for (int nf = 0; nf < 2; ++nf) { _Pragma("unroll") for (int ks = 0; ks < 2; ++ks) { \
      int r = wnb + (nh) * 32 + nf * 16 + lr; int k = ks * 32 + kg; \
      dst[nf][ks] = *(const short8*)((LP) + r * 64 + (k ^ ((r & 7) << 3))); } } }
#define MMA(bb, MB, NB) \
    __builtin_amdgcn_s_setprio(1); \
    _Pragma("unroll") for (int mf = 0; mf < 4; ++mf) { _Pragma("unroll") for (int nf = 0; nf < 2; ++nf) { _Pragma("unroll") for (int ks = 0; ks < 2; ++ks) { \
      acc[(MB) + mf][(NB) + nf] = __builtin_amdgcn_mfma_f32_16x16x32_bf16(a[mf][ks], bb[nf][ks], acc[(MB) + mf][(NB) + nf], 0, 0, 0); } } } \
    __builtin_amdgcn_s_setprio(0);

  // prologue: tile0 fully + B0,A0 of tile1 in flight; drain tile0 (vmcnt(4)).
  stA(0, 0, 0); stA(0, 1, 0); stB(0, 0, 0); stB(0, 1, 0);
  stB(1, 0, 1); stA(1, 0, 1);
  asm volatile("s_waitcnt vmcnt(4)" ::: "memory");
  __builtin_amdgcn_s_barrier();

  for (int i = 0; i < nIter; ++i) {
    const int t0 = 2 * i, t1 = t0 + 1;
    const bool pf = (i + 1 < nIter);
    const unsigned short* LA0 = lds[0][0];
    const unsigned short* LB0 = lds[0][1];
    const unsigned short* LA1 = lds[1][0];
    const unsigned short* LB1 = lds[1][1];

    // ---- tile t0 (buf0) ----
    // ph1: read A-sub(mh0)+B-sub(nh0); stage A1,B1(t1) -> buf1
    RD_A(LA0, 0); RD_B(b0, LB0, 0);
    stA(1, 1, t1); stB(1, 1, t1);
    __builtin_amdgcn_s_barrier();
    MMA(b0, 0, 0);
    __builtin_amdgcn_s_barrier();
    // ph2: read B-sub(nh1)
    RD_B(b1, LB0, 1);
    __builtin_amdgcn_s_barrier();
    MMA(b1, 0, 2);
    __builtin_amdgcn_s_barrier();
    // ph3: read A-sub(mh1); stage B0(t0+2) -> buf0 (B reads of buf0 done at ph2)
    RD_A(LA0, 1);
    if (pf) stB(0, 0, t0 + 2);
    __builtin_amdgcn_s_barrier();
    MMA(b0, 4, 0);
    __builtin_amdgcn_s_barrier();
    // ph4: stage A0(t0+2) (A reads of buf0 done at ph3); drain so tile t1 is fully resident
    if (pf) stA(0, 0, t0 + 2);
    if (pf) asm volatile("s_waitcnt vmcnt(4)" ::: "memory");
    else    asm volatile("s_waitcnt vmcnt(0)" ::: "memory");
    __builtin_amdgcn_s_barrier();
    MMA(b1, 4, 2);
    __builtin_amdgcn_s_barrier();

    // ---- tile t1 (buf1) ----
    // ph5: read subtiles; stage A1,B1(t0+2) -> buf0
    RD_A(LA1, 0); RD_B(b0, LB1, 0);
    if (pf) { stA(0, 1, t0 + 2); stB(0, 1, t0 + 2); }
    __builtin_amdgcn_s_barrier();
    MMA(b0, 0, 0);
    __builtin_amdgcn_s_barrier();
    // ph6
    RD_B(b1, LB1, 1);
    __builtin_amdgcn_s_barrier();
    MMA(b1, 0, 2);
    __builtin_amdgcn_s_barrier();
    // ph7: stage B0(t1+2) -> buf1 (B reads of buf1 done at ph6)
    RD_A(LA1, 1);
    if (pf) stB(1, 0, t1 + 2);
    __builtin_amdgcn_s_barrier();
    MMA(b0, 4, 0);
    __builtin_amdgcn_s_barrier();
    // ph8: stage A0(t1+2) -> buf1; drain so next tile t0 is fully resident
    if (pf) stA(1, 0, t1 + 2);
    if (pf) asm volatile("s_waitcnt vmcnt(4)" ::: "memory");
    else    asm volatile("s_waitcnt vmcnt(0)" ::: "memory");
    __builtin_amdgcn_s_barrier();
    MMA(b1, 4, 2);
    __builtin_amdgcn_s_barrier();
  }
#undef RD_A
#undef RD_B
#undef MMA

  const int er = row0 + wmb + ((l >> 4) << 2);
  const int ec = col0 + wnb + lr;
  #pragma unroll
  for (int mi = 0; mi < 8; ++mi)
    #pragma unroll
    for (int ni = 0; ni < 4; ++ni)
      #pragma unroll
      for (int j = 0; j < 4; ++j)
        epi_store<EPI>(acc[mi][ni][j], er + mi * 16 + j, ec + ni * 16, N, bias, aux, out);
}

// ---------------- chunked affine scan h_t = a_t*h_{t-1} + b_t ----------------
__global__ void scan_p1(const float* __restrict__ abd, float* __restrict__ aggA, float* __restrict__ aggB) {
  int id = blockIdx.x * 256 + threadIdx.x;          // B*NCH*1024 = 65536
  int c = id & 1023;
  int chunk = (id >> 10) & (NCH - 1);
  int bb = id >> 14;
  const float* base = abd + (size_t)(bb * L_ + chunk * CLEN) * 3072;
  float Aa = 1.f, Bv = 0.f;
  #pragma unroll 4
  for (int t = 0; t < CLEN; ++t) {
    float a = base[(size_t)t * 3072 + c];
    float b = base[(size_t)t * 3072 + 1024 + c];
    Aa *= a;
    Bv = a * Bv + b;
  }
  int o = (chunk * B_ + bb) * 1024 + c;
  aggA[o] = Aa; aggB[o] = Bv;
}

__global__ void scan_p2(const float* __restrict__ aggA, const float* __restrict__ aggB,
                        float* __restrict__ hinit) {
  int id = blockIdx.x * 256 + threadIdx.x;          // 4096
  float hc = 0.f;
  for (int ch = 0; ch < NCH; ++ch) {
    int o = ch * 4096 + id;
    hinit[o] = hc;
    hc = aggA[o] * hc + aggB[o];
  }
}

__global__ void scan_p3(const float* __restrict__ abd, const float* __restrict__ hinit,
                        unsigned short* __restrict__ hb16) {
  int id = blockIdx.x * 256 + threadIdx.x;
  int c = id & 1023;
  int chunk = (id >> 10) & (NCH - 1);
  int bb = id >> 14;
  const float* base = abd + (size_t)(bb * L_ + chunk * CLEN) * 3072;
  unsigned short* hb = hb16 + (size_t)(bb * L_ + chunk * CLEN) * 1024;
  float h = hinit[chunk * 4096 + bb * 1024 + c];
  #pragma unroll 4
  for (int t = 0; t < CLEN; ++t) {
    float a = base[(size_t)t * 3072 + c];
    float b = base[(size_t)t * 3072 + 1024 + c];
    h = a * h + b;
    hb[(size_t)t * 1024 + c] = f2bf(h);
  }
}

// ---------------- u = z + LN(z); outputs f32 + bf16 ----------------
__global__ __launch_bounds__(256)
void ln_res(const float* __restrict__ z, const float* __restrict__ lg, const float* __restrict__ lb,
            float* __restrict__ u32, unsigned short* __restrict__ u16) {
  int row = blockIdx.x;
  int t = threadIdx.x;
  const float4 zv = *(const float4*)(z + (size_t)row * 1024 + t * 4);
  float s = zv.x + zv.y + zv.z + zv.w;
  float sq = zv.x * zv.x + zv.y * zv.y + zv.z * zv.z + zv.w * zv.w;
  #pragma unroll
  for (int o = 32; o > 0; o >>= 1) { s += __shfl_down(s, o); sq += __shfl_down(sq, o); }
  __shared__ float ps[4], pq[4];
  if ((t & 63) == 0) { ps[t >> 6] = s; pq[t >> 6] = sq; }
  __syncthreads();
  s = ps[0] + ps[1] + ps[2] + ps[3];
  sq = pq[0] + pq[1] + pq[2] + pq[3];
  float mu = s * (1.f / 1024.f);
  float var = sq * (1.f / 1024.f) - mu * mu;
  float rs = rsqrtf(var + 1e-5f);
  const float4 gv = *(const float4*)(lg + t * 4);
  const float4 bv = *(const float4*)(lb + t * 4);
  float4 o;
  o.x = zv.x + (zv.x - mu) * rs * gv.x + bv.x;
  o.y = zv.y + (zv.y - mu) * rs * gv.y + bv.y;
  o.z = zv.z + (zv.z - mu) * rs * gv.z + bv.z;
  o.w = zv.w + (zv.w - mu) * rs * gv.w + bv.w;
  *(float4*)(u32 + (size_t)row * 1024 + t * 4) = o;
  ushort4 ob; ob.x = f2bf(o.x); ob.y = f2bf(o.y); ob.z = f2bf(o.z); ob.w = f2bf(o.w);
  *(ushort4*)(u16 + (size_t)row * 1024 + t * 4) = ob;
}

extern "C" void kernel_launch(void* const* d_in, const int* in_sizes, int n_in,
                              void* d_out, int out_size, void* d_ws, size_t ws_size,
                              hipStream_t stream) {
  const float* emb    = (const float*)d_in[0];
  const float* Wa     = (const float*)d_in[1];
  const float* ba     = (const float*)d_in[2];
  const float* Wb     = (const float*)d_in[3];
  const float* bb     = (const float*)d_in[4];
  const float* WD     = (const float*)d_in[5];
  const float* bD     = (const float*)d_in[6];
  const float* WC     = (const float*)d_in[7];
  const float* bC     = (const float*)d_in[8];
  const float* ffn1_w = (const float*)d_in[9];
  const float* ffn1_b = (const float*)d_in[10];
  const float* ffn2_w = (const float*)d_in[11];
  const float* ffn2_b = (const float*)d_in[12];
  const float* proj_w = (const float*)d_in[13];
  const float* proj_b = (const float*)d_in[14];
  const float* ln_g   = (const float*)d_in[15];
  const float* ln_b   = (const float*)d_in[16];

  char* p = (char*)d_ws;
  auto alloc = [&](size_t bytes) { char* r = p; p += (bytes + 255) & ~(size_t)255; return (void*)r; };

  float* abd   = (float*)alloc((size_t)ROWS * 3072 * 4);
  unsigned short* hb16 = (unsigned short*)alloc((size_t)ROWS * 1024 * 2);
  float* zbuf  = (float*)alloc((size_t)ROWS * 1024 * 4);
  float* u32   = (float*)alloc((size_t)ROWS * 1024 * 4);
  unsigned short* u16  = (unsigned short*)alloc((size_t)ROWS * 1024 * 2);
  unsigned short* embb = (unsigned short*)alloc((size_t)ROWS * 1024 * 2);
  unsigned short* wcat = (unsigned short*)alloc((size_t)3072 * 1024 * 2);
  unsigned short* f1t  = (unsigned short*)alloc((size_t)4096 * 1024 * 2);
  unsigned short* f2t  = (unsigned short*)alloc((size_t)4096 * 1024 * 2);
  unsigned short* pjt  = (unsigned short*)alloc((size_t)1024 * 1024 * 2);
  unsigned short* wcblk= (unsigned short*)alloc((size_t)1024 * 1024 * 2);
  float* biascat = (float*)alloc(3072 * 4);
  float* aggA  = (float*)alloc(65536 * 4);
  float* aggB  = (float*)alloc(65536 * 4);
  float* hinit = (float*)alloc(65536 * 4);
  // aliased (disjoint lifetimes):
  unsigned short* gbuf = (unsigned short*)abd;   // [ROWS][4096] bf16 (abd dead after head GEMM)
  unsigned short* vbuf = (unsigned short*)zbuf;  // [ROWS][1024] bf16 (zbuf dead after ln_res)

  dim3 tb(32, 8);
  cast_f32_bf16<<<ROWS * 1024 / 1024, 256, 0, stream>>>(emb, embb, ROWS * 1024);
  build_bias<<<12, 256, 0, stream>>>(ba, bb, bD, biascat);
  build_wcblk<<<1024 * 1024 / 256, 256, 0, stream>>>(WC, wcblk);
  transpose_cast<<<dim3(E_ / 32, DH_ / 32, H_), tb, 0, stream>>>(Wa, wcat, E_, DH_, 0);
  transpose_cast<<<dim3(E_ / 32, DH_ / 32, H_), tb, 0, stream>>>(Wb, wcat, E_, DH_, 1024);
  transpose_cast<<<dim3(E_ / 32, DH_ / 32, H_), tb, 0, stream>>>(WD, wcat, E_, DH_, 2048);
  transpose_cast<<<dim3(1024 / 32, 4096 / 32, 1), tb, 0, stream>>>(ffn1_w, f1t, 1024, 4096, 0);
  transpose_cast<<<dim3(4096 / 32, 1024 / 32, 1), tb, 0, stream>>>(ffn2_w, f2t, 4096, 1024, 0);
  transpose_cast<<<dim3(1024 / 32, 1024 / 32, 1), tb, 0, stream>>>(proj_w, pjt, 1024, 1024, 0);

  // G1: [8192,1024] x [1024,3072] -> abd (bias + tanh on a-cols)   [256^2 8-phase]
  gemm256<EPI_GATES><<<dim3(3072 / 256, ROWS / 256), 512, 0, stream>>>(
      embb, wcat, biascat, nullptr, abd, ROWS, 3072, 1024);

  scan_p1<<<65536 / 256, 256, 0, stream>>>(abd, aggA, aggB);
  scan_p2<<<4096 / 256, 256, 0, stream>>>(aggA, aggB, hinit);
  scan_p3<<<65536 / 256, 256, 0, stream>>>(abd, hinit, hb16);

  // head mix as block-diag GEMM: z = (h @ WCblk + bC) * d          [128^2, 512 wg]
  gemm_bt<EPI_HEAD><<<dim3(1024 / 128, ROWS / 128), 256, 0, stream>>>(
      hb16, wcblk, bC, abd + 2048, zbuf, ROWS, 1024, 1024);

  ln_res<<<ROWS, 256, 0, stream>>>(zbuf, ln_g, ln_b, u32, u16);

  // FFN1: [8192,1024] x [1024,4096] -> gelu -> gbuf (bf16)         [256^2 8-phase]
  gemm256<EPI_GELU><<<dim3(4096 / 256, ROWS / 256), 512, 0, stream>>>(
      u16, f1t, ffn1_b, nullptr, gbuf, ROWS, 4096, 1024);
  // FFN2: [8192,4096] x [4096,1024] + u -> vbuf (bf16)             [128^2, 512 wg]
  gemm_bt<EPI_RES><<<dim3(1024 / 128, ROWS / 128), 256, 0, stream>>>(
      gbuf, f2t, ffn2_b, u32, vbuf, ROWS, 1024, 4096);
  // proj: [8192,1024] x [1024,1024] -> d_out (f32)                 [128^2, 512 wg]
  gemm_bt<EPI_OUT><<<dim3(1024 / 128, ROWS / 128), 256, 0, stream>>>(
      vbuf, pjt, proj_b, nullptr, (float*)d_out, ROWS, 1024, 1024);
}

// Round 3
// 553.934 us; speedup vs baseline: 1.2395x; 1.0925x over previous
//
#include <hip/hip_runtime.h>
#include <hip/hip_bf16.h>
#include <math.h>

#define B_   4
#define L_   2048
#define E_   1024
#define H_   16
#define DH_  64
#define HID_ 1024
#define ROWS (B_*L_)      // 8192
#define NCH  16
#define CLEN (L_/NCH)     // 128

typedef __attribute__((ext_vector_type(8))) short short8;
typedef __attribute__((ext_vector_type(4))) float f32x4;

__device__ __forceinline__ unsigned short f2bf(float f) {
  union { float f; unsigned int i; } v; v.f = f;
  unsigned int r = v.i + 0x7fffu + ((v.i >> 16) & 1u);
  return (unsigned short)(r >> 16);
}
__device__ __forceinline__ float bf2f(unsigned int u) {
  union { unsigned int i; float f; } v; v.i = u << 16; return v.f;
}

__device__ __forceinline__ void gload16(const unsigned short* g, unsigned short* l) {
  __builtin_amdgcn_global_load_lds((const __attribute__((address_space(1))) void*)g,
                                   (__attribute__((address_space(3))) void*)l, 16, 0, 0);
}

// ---------------- elementwise cast f32 -> bf16 (4/thread) ----------------
__global__ void cast_f32_bf16(const float* __restrict__ src, unsigned short* __restrict__ dst, int n) {
  int i = (blockIdx.x * 256 + threadIdx.x) * 4;
  if (i < n) {
    float4 v = *(const float4*)(src + i);
    ushort4 o;
    o.x = f2bf(v.x); o.y = f2bf(v.y); o.z = f2bf(v.z); o.w = f2bf(v.w);
    *(ushort4*)(dst + i) = o;
  }
}

// ---------------- tiled transpose + cast ----------------
__global__ void transpose_cast(const float* __restrict__ src, unsigned short* __restrict__ dst,
                               int R, int C, int dstBase) {
  __shared__ float tile[32][33];
  src += (size_t)blockIdx.z * R * C;
  int dstRow0 = dstBase + blockIdx.z * C;
  int rb = blockIdx.x * 32, cb = blockIdx.y * 32;
  for (int i = threadIdx.y; i < 32; i += 8)
    tile[i][threadIdx.x] = src[(size_t)(rb + i) * C + cb + threadIdx.x];
  __syncthreads();
  for (int i = threadIdx.y; i < 32; i += 8)
    dst[(size_t)(dstRow0 + cb + i) * R + rb + threadIdx.x] = f2bf(tile[threadIdx.x][i]);
}

// ---------------- concat bias [ba|bb|bD] ----------------
__global__ void build_bias(const float* __restrict__ ba, const float* __restrict__ bb,
                           const float* __restrict__ bD, float* __restrict__ bias) {
  int i = blockIdx.x * 256 + threadIdx.x;
  const float* src = (i < 1024) ? ba : ((i < 2048) ? bb : bD);
  bias[i] = src[i & 1023];
}

// ---------------- compact diag WC^T: wcd[c][kl] (1024 x 128) ----------------
// global k = (c>>7)*128 + kl ; nonzero iff kl>>6 == (c>>6)&1 ; value WC[c>>6][kl&63][c&63]
__global__ void build_wcd(const float* __restrict__ WC, unsigned short* __restrict__ dst) {
  int i = blockIdx.x * 256 + threadIdx.x;     // over 1024*128
  int c = i >> 7, kl = i & 127;
  float v = ((kl >> 6) == ((c >> 6) & 1)) ? WC[(size_t)(c >> 6) * 4096 + (kl & 63) * 64 + (c & 63)] : 0.f;
  dst[i] = f2bf(v);
}

// ---------------- fused epilogues ----------------
#define EPI_GATES 0   // bf16: a->out interleaved(2c), b->out(2c+1), d->out2; tanh on a
#define EPI_GELU  1   // bf16 out; exact gelu
#define EPI_RES   2   // bf16 out; + aux (f32 residual, stride N)
#define EPI_OUT   3   // f32 out
#define EPI_HEAD  4   // f32 out; (acc+bias)*aux  (aux bf16, stride 1024)

template<int EPI>
__device__ __forceinline__ void epi_store(float xa, int rr, int cc, int N,
                                          const float* __restrict__ bias,
                                          const void* __restrict__ aux,
                                          void* __restrict__ out, void* __restrict__ out2) {
  float x = xa + bias[cc];
  if (EPI == EPI_GATES) {
    if (cc < HID_) {
      x = tanhf(x);
      ((unsigned short*)out)[(size_t)rr * 2048 + (cc << 1)] = f2bf(x);
    } else if (cc < 2048) {
      ((unsigned short*)out)[(size_t)rr * 2048 + ((cc - 1024) << 1) + 1] = f2bf(x);
    } else {
      ((unsigned short*)out2)[(size_t)rr * 1024 + (cc - 2048)] = f2bf(x);
    }
  } else if (EPI == EPI_GELU) {
    x = 0.5f * x * (1.f + erff(x * 0.70710678118654752f));
    ((unsigned short*)out)[(size_t)rr * N + cc] = f2bf(x);
  } else if (EPI == EPI_RES) {
    x += ((const float*)aux)[(size_t)rr * N + cc];
    ((unsigned short*)out)[(size_t)rr * N + cc] = f2bf(x);
  } else if (EPI == EPI_HEAD) {
    x *= bf2f(((const unsigned short*)aux)[(size_t)rr * 1024 + cc]);
    ((float*)out)[(size_t)rr * N + cc] = x;
  } else {
    ((float*)out)[(size_t)rr * N + cc] = x;
  }
}

// ---------------- 128x128 m97-structure GEMM with strides + diag offset ----------------
template<int EPI, int DIAG>
__global__ __launch_bounds__(256)
void gemm_bt(const unsigned short* __restrict__ A, int lda,
             const unsigned short* __restrict__ Bt, int ldb,
             const float* __restrict__ bias, const void* __restrict__ aux,
             void* __restrict__ out, void* __restrict__ out2, int M, int N, int K) {
  __shared__ unsigned short lA[128 * 32];
  __shared__ unsigned short lB[128 * 32];
  const int tid = threadIdx.x;
  const int w = tid >> 6, l = tid & 63;
  // T1 XCD swizzle (nwg % 8 == 0)
  const int gx = gridDim.x, nwg = gx * gridDim.y;
  const int o = blockIdx.y * gx + blockIdx.x;
  const int lin = (o & 7) * (nwg >> 3) + (o >> 3);
  const int row0 = (lin / gx) * 128, col0 = (lin % gx) * 128;
  const int kOff = DIAG ? col0 : 0;

  const int rA0 = w * 16 + (l >> 2);
  const int rA1 = (4 + w) * 16 + (l >> 2);
  const int koff = (l & 3) * 8;
  const unsigned short* gA0 = A + (size_t)(row0 + rA0) * lda + kOff + koff;
  const unsigned short* gA1 = A + (size_t)(row0 + rA1) * lda + kOff + koff;
  const unsigned short* gB0 = Bt + (size_t)(col0 + rA0) * ldb + koff;
  const unsigned short* gB1 = Bt + (size_t)(col0 + rA1) * ldb + koff;
  unsigned short* lA0 = lA + w * 512;
  unsigned short* lA1 = lA + (4 + w) * 512;
  unsigned short* lB0 = lB + w * 512;
  unsigned short* lB1 = lB + (4 + w) * 512;

  const int wr = (w >> 1) * 64, wc = (w & 1) * 64;
  f32x4 acc[4][4];
  #pragma unroll
  for (int m = 0; m < 4; m++)
    #pragma unroll
    for (int n = 0; n < 4; n++) acc[m][n] = (f32x4){0.f, 0.f, 0.f, 0.f};

  const int arow = wr + (l & 15);
  const int brow = wc + (l & 15);
  const int kg = (l >> 4) * 8;

  for (int kt = 0; kt < K; kt += 32) {
    __syncthreads();
    gload16(gA0 + kt, lA0);
    gload16(gA1 + kt, lA1);
    gload16(gB0 + kt, lB0);
    gload16(gB1 + kt, lB1);
    __syncthreads();
    short8 af[4], bfr[4];
    #pragma unroll
    for (int m = 0; m < 4; m++) af[m]  = *(const short8*)(lA + (arow + m * 16) * 32 + kg);
    #pragma unroll
    for (int n = 0; n < 4; n++) bfr[n] = *(const short8*)(lB + (brow + n * 16) * 32 + kg);
    #pragma unroll
    for (int m = 0; m < 4; m++)
      #pragma unroll
      for (int n = 0; n < 4; n++)
        acc[m][n] = __builtin_amdgcn_mfma_f32_16x16x32_bf16(af[m], bfr[n], acc[m][n], 0, 0, 0);
  }

  const int er = row0 + wr + ((l >> 4) << 2);
  const int ec = col0 + wc + (l & 15);
  #pragma unroll
  for (int m = 0; m < 4; m++)
    #pragma unroll
    for (int n = 0; n < 4; n++)
      #pragma unroll
      for (int j = 0; j < 4; j++)
        epi_store<EPI>(acc[m][n][j], er + m * 16 + j, ec + n * 16, N, bias, aux, out, out2);
}

// ---------------- 256x256 8-phase GEMM (T1+T2+T3/T4+T5) ----------------
template<int EPI>
__global__ __launch_bounds__(512, 2)
void gemm256(const unsigned short* __restrict__ A, const unsigned short* __restrict__ Bt,
             const float* __restrict__ bias, const void* __restrict__ aux,
             void* __restrict__ out, void* __restrict__ out2, int M, int N, int K) {
  __shared__ unsigned short lds[2][2][256 * 64];
  const int tid = threadIdx.x;
  const int w = tid >> 6, l = tid & 63;
  const int wm = w >> 2, wn = w & 3;
  const int gx = gridDim.x, nwg = gx * gridDim.y;
  const int o = blockIdx.y * gx + blockIdx.x;
  const int lin = (o & 7) * (nwg >> 3) + (o >> 3);
  const int row0 = (lin / gx) * 256, col0 = (lin % gx) * 256;
  const int lr = l & 15, kg = (l >> 4) << 3;
  const int wmb = wm * 128, wnb = wn * 64;
  const int nIter = K >> 7;

  const int srow = w * 8 + (l >> 3);
  const int kswz = (((l & 7) ^ (l >> 3)) << 3);

  f32x4 acc[8][4];
  #pragma unroll
  for (int m = 0; m < 8; m++)
    #pragma unroll
    for (int n = 0; n < 4; n++) acc[m][n] = (f32x4){0.f, 0.f, 0.f, 0.f};

  short8 a[4][2], b0[2][2], b1[2][2];

  auto stA = [&](int buf, int hh, int kt) {
    const unsigned short* g = A + (size_t)(row0 + hh * 128 + srow) * K + kt * 64 + kswz;
    unsigned short* d = &lds[buf][0][hh * 8192 + w * 512];
    gload16(g, d);
    gload16(g + (size_t)64 * K, d + 4096);
  };
  auto stB = [&](int buf, int hh, int kt) {
    const unsigned short* g = Bt + (size_t)(col0 + hh * 128 + srow) * K + kt * 64 + kswz;
    unsigned short* d = &lds[buf][1][hh * 8192 + w * 512];
    gload16(g, d);
    gload16(g + (size_t)64 * K, d + 4096);
  };

#define RD_A(LP, mh) { _Pragma("unroll") for (int mf = 0; mf < 4; ++mf) { _Pragma("unroll") for (int ks = 0; ks < 2; ++ks) { \
      int r = wmb + (mh) * 64 + mf * 16 + lr; int k = ks * 32 + kg; \
      a[mf][ks] = *(const short8*)((LP) + r * 64 + (k ^ ((r & 7) << 3))); } } }
#define RD_B(dst, LP, nh) { _Pragma("unroll") for (int nf = 0; nf < 2; ++nf) { _Pragma("unroll") for (int ks = 0; ks < 2; ++ks) { \
      int r = wnb + (nh) * 32 + nf * 16 + lr; int k = ks * 32 + kg; \
      dst[nf][ks] = *(const short8*)((LP) + r * 64 + (k ^ ((r & 7) << 3))); } } }
#define MMA(bb, MB, NB) \
    __builtin_amdgcn_s_setprio(1); \
    _Pragma("unroll") for (int mf = 0; mf < 4; ++mf) { _Pragma("unroll") for (int nf = 0; nf < 2; ++nf) { _Pragma("unroll") for (int ks = 0; ks < 2; ++ks) { \
      acc[(MB) + mf][(NB) + nf] = __builtin_amdgcn_mfma_f32_16x16x32_bf16(a[mf][ks], bb[nf][ks], acc[(MB) + mf][(NB) + nf], 0, 0, 0); } } } \
    __builtin_amdgcn_s_setprio(0);

  stA(0, 0, 0); stA(0, 1, 0); stB(0, 0, 0); stB(0, 1, 0);
  stB(1, 0, 1); stA(1, 0, 1);
  asm volatile("s_waitcnt vmcnt(4)" ::: "memory");
  __builtin_amdgcn_s_barrier();

  for (int i = 0; i < nIter; ++i) {
    const int t0 = 2 * i, t1 = t0 + 1;
    const bool pf = (i + 1 < nIter);
    const unsigned short* LA0 = lds[0][0];
    const unsigned short* LB0 = lds[0][1];
    const unsigned short* LA1 = lds[1][0];
    const unsigned short* LB1 = lds[1][1];

    RD_A(LA0, 0); RD_B(b0, LB0, 0);
    stA(1, 1, t1); stB(1, 1, t1);
    __builtin_amdgcn_s_barrier();
    MMA(b0, 0, 0);
    __builtin_amdgcn_s_barrier();
    RD_B(b1, LB0, 1);
    __builtin_amdgcn_s_barrier();
    MMA(b1, 0, 2);
    __builtin_amdgcn_s_barrier();
    RD_A(LA0, 1);
    if (pf) stB(0, 0, t0 + 2);
    __builtin_amdgcn_s_barrier();
    MMA(b0, 4, 0);
    __builtin_amdgcn_s_barrier();
    if (pf) stA(0, 0, t0 + 2);
    if (pf) asm volatile("s_waitcnt vmcnt(4)" ::: "memory");
    else    asm volatile("s_waitcnt vmcnt(0)" ::: "memory");
    __builtin_amdgcn_s_barrier();
    MMA(b1, 4, 2);
    __builtin_amdgcn_s_barrier();

    RD_A(LA1, 0); RD_B(b0, LB1, 0);
    if (pf) { stA(0, 1, t0 + 2); stB(0, 1, t0 + 2); }
    __builtin_amdgcn_s_barrier();
    MMA(b0, 0, 0);
    __builtin_amdgcn_s_barrier();
    RD_B(b1, LB1, 1);
    __builtin_amdgcn_s_barrier();
    MMA(b1, 0, 2);
    __builtin_amdgcn_s_barrier();
    RD_A(LA1, 1);
    if (pf) stB(1, 0, t1 + 2);
    __builtin_amdgcn_s_barrier();
    MMA(b0, 4, 0);
    __builtin_amdgcn_s_barrier();
    if (pf) stA(1, 0, t1 + 2);
    if (pf) asm volatile("s_waitcnt vmcnt(4)" ::: "memory");
    else    asm volatile("s_waitcnt vmcnt(0)" ::: "memory");
    __builtin_amdgcn_s_barrier();
    MMA(b1, 4, 2);
    __builtin_amdgcn_s_barrier();
  }
#undef RD_A
#undef RD_B
#undef MMA

  const int er = row0 + wmb + ((l >> 4) << 2);
  const int ec = col0 + wnb + lr;
  #pragma unroll
  for (int mi = 0; mi < 8; ++mi)
    #pragma unroll
    for (int ni = 0; ni < 4; ++ni)
      #pragma unroll
      for (int j = 0; j < 4; ++j)
        epi_store<EPI>(acc[mi][ni][j], er + mi * 16 + j, ec + ni * 16, N, bias, aux, out, out2);
}

// ---------------- 256x128 8-phase GEMM (for N=1024 shapes: grid 8x32 = 256 wg) ----------------
// waves: 4M x 2N, per-wave 64x64. LDS 96KB. 6 loads/tile -> counted vmcnt(3).
template<int EPI>
__global__ __launch_bounds__(512, 2)
void gemm256x128(const unsigned short* __restrict__ A, const unsigned short* __restrict__ Bt,
                 const float* __restrict__ bias, const void* __restrict__ aux,
                 void* __restrict__ out, void* __restrict__ out2, int M, int N, int K) {
  __shared__ unsigned short lA2[2][256 * 64];
  __shared__ unsigned short lB2[2][128 * 64];
  const int tid = threadIdx.x;
  const int w = tid >> 6, l = tid & 63;
  const int wm = w >> 1, wn = w & 1;
  const int gx = gridDim.x, nwg = gx * gridDim.y;
  const int o = blockIdx.y * gx + blockIdx.x;
  const int lin = (o & 7) * (nwg >> 3) + (o >> 3);
  const int row0 = (lin / gx) * 256, col0 = (lin % gx) * 128;
  const int lr = l & 15, kg = (l >> 4) << 3;
  const int nIter = K >> 7;

  const int srow = w * 8 + (l >> 3);
  const int kswz = (((l & 7) ^ (l >> 3)) << 3);

  f32x4 acc[4][4];
  #pragma unroll
  for (int m = 0; m < 4; m++)
    #pragma unroll
    for (int n = 0; n < 4; n++) acc[m][n] = (f32x4){0.f, 0.f, 0.f, 0.f};

  short8 a[2][2], b0[2][2], b1[2][2];

  auto stA = [&](int buf, int hh, int kt) {   // 128-row A half: 2 loads
    const unsigned short* g = A + (size_t)(row0 + hh * 128 + srow) * K + kt * 64 + kswz;
    unsigned short* d = &lA2[buf][hh * 8192 + w * 512];
    gload16(g, d);
    gload16(g + (size_t)64 * K, d + 4096);
  };
  auto stB = [&](int buf, int hh, int kt) {   // 64-row B half: 1 load
    const unsigned short* g = Bt + (size_t)(col0 + hh * 64 + srow) * K + kt * 64 + kswz;
    gload16(g, &lB2[buf][hh * 4096 + w * 512]);
  };

#define RDA2(buf, mh) { _Pragma("unroll") for (int mf = 0; mf < 2; ++mf) { _Pragma("unroll") for (int ks = 0; ks < 2; ++ks) { \
      int r = wm * 64 + (mh) * 32 + mf * 16 + lr; int k = ks * 32 + kg; \
      a[mf][ks] = *(const short8*)(&lA2[buf][r * 64 + (k ^ ((r & 7) << 3))]); } } }
#define RDB2(dst, buf, nh) { _Pragma("unroll") for (int nf = 0; nf < 2; ++nf) { _Pragma("unroll") for (int ks = 0; ks < 2; ++ks) { \
      int r = wn * 64 + (nh) * 32 + nf * 16 + lr; int k = ks * 32 + kg; \
      dst[nf][ks] = *(const short8*)(&lB2[buf][r * 64 + (k ^ ((r & 7) << 3))]); } } }
#define MMA2(bb, MB, NB) \
    __builtin_amdgcn_s_setprio(1); \
    _Pragma("unroll") for (int mf = 0; mf < 2; ++mf) { _Pragma("unroll") for (int nf = 0; nf < 2; ++nf) { _Pragma("unroll") for (int ks = 0; ks < 2; ++ks) { \
      acc[(MB) + mf][(NB) + nf] = __builtin_amdgcn_mfma_f32_16x16x32_bf16(a[mf][ks], bb[nf][ks], acc[(MB) + mf][(NB) + nf], 0, 0, 0); } } } \
    __builtin_amdgcn_s_setprio(0);

  // prologue: tile0 (6 loads) + t1 partial (3 loads); vmcnt(3) -> t0 resident
  stA(0, 0, 0); stA(0, 1, 0); stB(0, 0, 0); stB(0, 1, 0);
  stB(1, 0, 1); stA(1, 0, 1);
  asm volatile("s_waitcnt vmcnt(3)" ::: "memory");
  __builtin_amdgcn_s_barrier();

  for (int i = 0; i < nIter; ++i) {
    const int t0 = 2 * i, t1 = t0 + 1;
    const bool pf = (i + 1 < nIter);

    // ---- tile t0 (buf0) ----
    RDA2(0, 0); RDB2(b0, 0, 0);
    stA(1, 1, t1); stB(1, 1, t1);          // finish t1 (3 loads)
    __builtin_amdgcn_s_barrier();
    MMA2(b0, 0, 0);
    __builtin_amdgcn_s_barrier();
    RDB2(b1, 0, 1);
    __builtin_amdgcn_s_barrier();
    MMA2(b1, 0, 2);
    __builtin_amdgcn_s_barrier();
    RDA2(0, 1);
    if (pf) stB(0, 0, t0 + 2);             // 1 load
    __builtin_amdgcn_s_barrier();
    MMA2(b0, 2, 0);
    __builtin_amdgcn_s_barrier();
    if (pf) stA(0, 0, t0 + 2);             // 2 loads ; outstanding after t1 = 3
    if (pf) asm volatile("s_waitcnt vmcnt(3)" ::: "memory");
    else    asm volatile("s_waitcnt vmcnt(0)" ::: "memory");
    __builtin_amdgcn_s_barrier();
    MMA2(b1, 2, 2);
    __builtin_amdgcn_s_barrier();

    // ---- tile t1 (buf1) ----
    RDA2(1, 0); RDB2(b0, 1, 0);
    if (pf) { stA(0, 1, t0 + 2); stB(0, 1, t0 + 2); }   // 3 loads
    __builtin_amdgcn_s_barrier();
    MMA2(b0, 0, 0);
    __builtin_amdgcn_s_barrier();
    RDB2(b1, 1, 1);
    __builtin_amdgcn_s_barrier();
    MMA2(b1, 0, 2);
    __builtin_amdgcn_s_barrier();
    RDA2(1, 1);
    if (pf) stB(1, 0, t1 + 2);             // 1 load
    __builtin_amdgcn_s_barrier();
    MMA2(b0, 2, 0);
    __builtin_amdgcn_s_barrier();
    if (pf) stA(1, 0, t1 + 2);             // 2 loads ; outstanding after t0+2 = 3
    if (pf) asm volatile("s_waitcnt vmcnt(3)" ::: "memory");
    else    asm volatile("s_waitcnt vmcnt(0)" ::: "memory");
    __builtin_amdgcn_s_barrier();
    MMA2(b1, 2, 2);
    __builtin_amdgcn_s_barrier();
  }
#undef RDA2
#undef RDB2
#undef MMA2

  const int er = row0 + wm * 64 + ((l >> 4) << 2);
  const int ec = col0 + wn * 64 + lr;
  #pragma unroll
  for (int mi = 0; mi < 4; ++mi)
    #pragma unroll
    for (int ni = 0; ni < 4; ++ni)
      #pragma unroll
      for (int j = 0; j < 4; ++j)
        epi_store<EPI>(acc[mi][ni][j], er + mi * 16 + j, ec + ni * 16, N, bias, aux, out, out2);
}

// ---------------- chunked affine scan (bf16 inputs, f32 accum) ----------------
// ab16: [ROWS][2048] bf16, (a,b) interleaved pairs
__global__ void scan_p1(const unsigned short* __restrict__ ab16, float* __restrict__ aggA, float* __restrict__ aggB) {
  int id = blockIdx.x * 256 + threadIdx.x;
  int c = id & 1023;
  int chunk = (id >> 10) & (NCH - 1);
  int bb = id >> 14;
  const unsigned short* base = ab16 + (size_t)(bb * L_ + chunk * CLEN) * 2048 + 2 * c;
  float Aa = 1.f, Bv = 0.f;
  #pragma unroll 4
  for (int t = 0; t < CLEN; ++t) {
    unsigned int v = *(const unsigned int*)(base + (size_t)t * 2048);
    float a = bf2f(v & 0xffffu);
    float b = bf2f(v >> 16);
    Aa *= a;
    Bv = a * Bv + b;
  }
  int o = (chunk * B_ + bb) * 1024 + c;
  aggA[o] = Aa; aggB[o] = Bv;
}

__global__ void scan_p2(const float* __restrict__ aggA, const float* __restrict__ aggB,
                        float* __restrict__ hinit) {
  int id = blockIdx.x * 256 + threadIdx.x;
  float hc = 0.f;
  for (int ch = 0; ch < NCH; ++ch) {
    int o = ch * 4096 + id;
    hinit[o] = hc;
    hc = aggA[o] * hc + aggB[o];
  }
}

__global__ void scan_p3(const unsigned short* __restrict__ ab16, const float* __restrict__ hinit,
                        unsigned short* __restrict__ hb16) {
  int id = blockIdx.x * 256 + threadIdx.x;
  int c = id & 1023;
  int chunk = (id >> 10) & (NCH - 1);
  int bb = id >> 14;
  const unsigned short* base = ab16 + (size_t)(bb * L_ + chunk * CLEN) * 2048 + 2 * c;
  unsigned short* hb = hb16 + (size_t)(bb * L_ + chunk * CLEN) * 1024;
  float h = hinit[chunk * 4096 + bb * 1024 + c];
  #pragma unroll 4
  for (int t = 0; t < CLEN; ++t) {
    unsigned int v = *(const unsigned int*)(base + (size_t)t * 2048);
    float a = bf2f(v & 0xffffu);
    float b = bf2f(v >> 16);
    h = a * h + b;
    hb[(size_t)t * 1024 + c] = f2bf(h);
  }
}

// ---------------- u = z + LN(z); outputs f32 + bf16 ----------------
__global__ __launch_bounds__(256)
void ln_res(const float* __restrict__ z, const float* __restrict__ lg, const float* __restrict__ lb,
            float* __restrict__ u32, unsigned short* __restrict__ u16) {
  int row = blockIdx.x;
  int t = threadIdx.x;
  const float4 zv = *(const float4*)(z + (size_t)row * 1024 + t * 4);
  float s = zv.x + zv.y + zv.z + zv.w;
  float sq = zv.x * zv.x + zv.y * zv.y + zv.z * zv.z + zv.w * zv.w;
  #pragma unroll
  for (int o = 32; o > 0; o >>= 1) { s += __shfl_down(s, o); sq += __shfl_down(sq, o); }
  __shared__ float ps[4], pq[4];
  if ((t & 63) == 0) { ps[t >> 6] = s; pq[t >> 6] = sq; }
  __syncthreads();
  s = ps[0] + ps[1] + ps[2] + ps[3];
  sq = pq[0] + pq[1] + pq[2] + pq[3];
  float mu = s * (1.f / 1024.f);
  float var = sq * (1.f / 1024.f) - mu * mu;
  float rs = rsqrtf(var + 1e-5f);
  const float4 gv = *(const float4*)(lg + t * 4);
  const float4 bv = *(const float4*)(lb + t * 4);
  float4 o;
  o.x = zv.x + (zv.x - mu) * rs * gv.x + bv.x;
  o.y = zv.y + (zv.y - mu) * rs * gv.y + bv.y;
  o.z = zv.z + (zv.z - mu) * rs * gv.z + bv.z;
  o.w = zv.w + (zv.w - mu) * rs * gv.w + bv.w;
  *(float4*)(u32 + (size_t)row * 1024 + t * 4) = o;
  ushort4 ob; ob.x = f2bf(o.x); ob.y = f2bf(o.y); ob.z = f2bf(o.z); ob.w = f2bf(o.w);
  *(ushort4*)(u16 + (size_t)row * 1024 + t * 4) = ob;
}

extern "C" void kernel_launch(void* const* d_in, const int* in_sizes, int n_in,
                              void* d_out, int out_size, void* d_ws, size_t ws_size,
                              hipStream_t stream) {
  const float* emb    = (const float*)d_in[0];
  const float* Wa     = (const float*)d_in[1];
  const float* ba     = (const float*)d_in[2];
  const float* Wb     = (const float*)d_in[3];
  const float* bb     = (const float*)d_in[4];
  const float* WD     = (const float*)d_in[5];
  const float* bD     = (const float*)d_in[6];
  const float* WC     = (const float*)d_in[7];
  const float* bC     = (const float*)d_in[8];
  const float* ffn1_w = (const float*)d_in[9];
  const float* ffn1_b = (const float*)d_in[10];
  const float* ffn2_w = (const float*)d_in[11];
  const float* ffn2_b = (const float*)d_in[12];
  const float* proj_w = (const float*)d_in[13];
  const float* proj_b = (const float*)d_in[14];
  const float* ln_g   = (const float*)d_in[15];
  const float* ln_b   = (const float*)d_in[16];

  char* p = (char*)d_ws;
  auto alloc = [&](size_t bytes) { char* r = p; p += (bytes + 255) & ~(size_t)255; return (void*)r; };

  // order matters: gbuf (64MB) aliases ab16+d16+hb16 (32+16+16MB, dead before FFN1)
  unsigned short* ab16 = (unsigned short*)alloc((size_t)ROWS * 2048 * 2);  // 32MB (a,b) pairs
  unsigned short* d16  = (unsigned short*)alloc((size_t)ROWS * 1024 * 2);  // 16MB d gate
  unsigned short* hb16 = (unsigned short*)alloc((size_t)ROWS * 1024 * 2);  // 16MB scan h
  float* zbuf  = (float*)alloc((size_t)ROWS * 1024 * 4);                   // 32MB
  float* u32   = (float*)alloc((size_t)ROWS * 1024 * 4);
  unsigned short* u16  = (unsigned short*)alloc((size_t)ROWS * 1024 * 2);
  unsigned short* embb = (unsigned short*)alloc((size_t)ROWS * 1024 * 2);
  unsigned short* wcat = (unsigned short*)alloc((size_t)3072 * 1024 * 2);
  unsigned short* f1t  = (unsigned short*)alloc((size_t)4096 * 1024 * 2);
  unsigned short* f2t  = (unsigned short*)alloc((size_t)4096 * 1024 * 2);
  unsigned short* pjt  = (unsigned short*)alloc((size_t)1024 * 1024 * 2);
  unsigned short* wcd  = (unsigned short*)alloc((size_t)1024 * 128 * 2);
  float* biascat = (float*)alloc(3072 * 4);
  float* aggA  = (float*)alloc(65536 * 4);
  float* aggB  = (float*)alloc(65536 * 4);
  float* hinit = (float*)alloc(65536 * 4);
  // aliases (disjoint lifetimes):
  unsigned short* gbuf = ab16;                  // [ROWS][4096] bf16, written by FFN1 (after head)
  unsigned short* vbuf = (unsigned short*)zbuf; // [ROWS][1024] bf16, written by FFN2 (after ln_res)

  dim3 tb(32, 8);
  cast_f32_bf16<<<ROWS * 1024 / 1024, 256, 0, stream>>>(emb, embb, ROWS * 1024);
  build_bias<<<12, 256, 0, stream>>>(ba, bb, bD, biascat);
  build_wcd<<<1024 * 128 / 256, 256, 0, stream>>>(WC, wcd);
  transpose_cast<<<dim3(E_ / 32, DH_ / 32, H_), tb, 0, stream>>>(Wa, wcat, E_, DH_, 0);
  transpose_cast<<<dim3(E_ / 32, DH_ / 32, H_), tb, 0, stream>>>(Wb, wcat, E_, DH_, 1024);
  transpose_cast<<<dim3(E_ / 32, DH_ / 32, H_), tb, 0, stream>>>(WD, wcat, E_, DH_, 2048);
  transpose_cast<<<dim3(1024 / 32, 4096 / 32, 1), tb, 0, stream>>>(ffn1_w, f1t, 1024, 4096, 0);
  transpose_cast<<<dim3(4096 / 32, 1024 / 32, 1), tb, 0, stream>>>(ffn2_w, f2t, 4096, 1024, 0);
  transpose_cast<<<dim3(1024 / 32, 1024 / 32, 1), tb, 0, stream>>>(proj_w, pjt, 1024, 1024, 0);

  // G1: [8192,1024]x[1024,3072] -> ab16 (interleaved a,b; tanh on a) + d16
  gemm256<EPI_GATES><<<dim3(3072 / 256, ROWS / 256), 512, 0, stream>>>(
      embb, wcat, biascat, nullptr, ab16, d16, ROWS, 3072, 1024);

  scan_p1<<<65536 / 256, 256, 0, stream>>>(ab16, aggA, aggB);
  scan_p2<<<4096 / 256, 256, 0, stream>>>(aggA, aggB, hinit);
  scan_p3<<<65536 / 256, 256, 0, stream>>>(ab16, hinit, hb16);

  // head: z = (h @ WC_diag + bC) * d ; K=128 diag window per col-block
  gemm_bt<EPI_HEAD, 1><<<dim3(1024 / 128, ROWS / 128), 256, 0, stream>>>(
      hb16, 1024, wcd, 128, bC, d16, zbuf, nullptr, ROWS, 1024, 128);

  ln_res<<<ROWS, 256, 0, stream>>>(zbuf, ln_g, ln_b, u32, u16);

  // FFN1: [8192,1024]x[1024,4096] -> gelu -> gbuf
  gemm256<EPI_GELU><<<dim3(4096 / 256, ROWS / 256), 512, 0, stream>>>(
      u16, f1t, ffn1_b, nullptr, gbuf, nullptr, ROWS, 4096, 1024);
  // FFN2: [8192,4096]x[4096,1024] + u -> vbuf      [256x128 8-phase, 256 wg]
  gemm256x128<EPI_RES><<<dim3(1024 / 128, ROWS / 256), 512, 0, stream>>>(
      gbuf, f2t, ffn2_b, u32, vbuf, nullptr, ROWS, 1024, 4096);
  // proj: [8192,1024]x[1024,1024] -> d_out (f32)   [256x128 8-phase, 256 wg]
  gemm256x128<EPI_OUT><<<dim3(1024 / 128, ROWS / 256), 512, 0, stream>>>(
      vbuf, pjt, proj_b, nullptr, (float*)d_out, nullptr, ROWS, 1024, 1024);
}

// Round 4
// 525.725 us; speedup vs baseline: 1.3060x; 1.0537x over previous
//
#include <hip/hip_runtime.h>
#include <hip/hip_bf16.h>
#include <math.h>

#define B_   4
#define L_   2048
#define E_   1024
#define H_   16
#define DH_  64
#define HID_ 1024
#define ROWS (B_*L_)      // 8192
#define NCH  16
#define CLEN (L_/NCH)     // 128

typedef __attribute__((ext_vector_type(8))) short short8;
typedef __attribute__((ext_vector_type(4))) float f32x4;

__device__ __forceinline__ unsigned short f2bf(float f) {
  union { float f; unsigned int i; } v; v.f = f;
  unsigned int r = v.i + 0x7fffu + ((v.i >> 16) & 1u);
  return (unsigned short)(r >> 16);
}
__device__ __forceinline__ float bf2f(unsigned int u) {
  union { unsigned int i; float f; } v; v.i = u << 16; return v.f;
}

__device__ __forceinline__ void gload16(const unsigned short* g, unsigned short* l) {
  __builtin_amdgcn_global_load_lds((const __attribute__((address_space(1))) void*)g,
                                   (__attribute__((address_space(3))) void*)l, 16, 0, 0);
}

// ---------------- elementwise cast f32 -> bf16 (4/thread) ----------------
__global__ void cast_f32_bf16(const float* __restrict__ src, unsigned short* __restrict__ dst, int n) {
  int i = (blockIdx.x * 256 + threadIdx.x) * 4;
  if (i < n) {
    float4 v = *(const float4*)(src + i);
    ushort4 o;
    o.x = f2bf(v.x); o.y = f2bf(v.y); o.z = f2bf(v.z); o.w = f2bf(v.w);
    *(ushort4*)(dst + i) = o;
  }
}

// ---------------- tiled transpose + cast ----------------
__global__ void transpose_cast(const float* __restrict__ src, unsigned short* __restrict__ dst,
                               int R, int C, int dstBase) {
  __shared__ float tile[32][33];
  src += (size_t)blockIdx.z * R * C;
  int dstRow0 = dstBase + blockIdx.z * C;
  int rb = blockIdx.x * 32, cb = blockIdx.y * 32;
  for (int i = threadIdx.y; i < 32; i += 8)
    tile[i][threadIdx.x] = src[(size_t)(rb + i) * C + cb + threadIdx.x];
  __syncthreads();
  for (int i = threadIdx.y; i < 32; i += 8)
    dst[(size_t)(dstRow0 + cb + i) * R + rb + threadIdx.x] = f2bf(tile[threadIdx.x][i]);
}

// ---------------- concat bias [ba|bb|bD] ----------------
__global__ void build_bias(const float* __restrict__ ba, const float* __restrict__ bb,
                           const float* __restrict__ bD, float* __restrict__ bias) {
  int i = blockIdx.x * 256 + threadIdx.x;
  const float* src = (i < 1024) ? ba : ((i < 2048) ? bb : bD);
  bias[i] = src[i & 1023];
}

// ---------------- compact diag WC^T: wcd[c][kl] (1024 x 128) ----------------
__global__ void build_wcd(const float* __restrict__ WC, unsigned short* __restrict__ dst) {
  int i = blockIdx.x * 256 + threadIdx.x;     // over 1024*128
  int c = i >> 7, kl = i & 127;
  float v = ((kl >> 6) == ((c >> 6) & 1)) ? WC[(size_t)(c >> 6) * 4096 + (kl & 63) * 64 + (c & 63)] : 0.f;
  dst[i] = f2bf(v);
}

// ---------------- fused epilogues ----------------
#define EPI_GATES 0   // bf16: a->out interleaved(2c), b->out(2c+1), d->out2; tanh on a
#define EPI_GELU  1   // bf16 out; exact gelu
#define EPI_RES   2   // bf16 out; + aux (f32 residual, stride N)
#define EPI_OUT   3   // f32 out
#define EPI_HEAD  4   // f32 out; (acc+bias)*aux  (aux bf16, stride 1024)

template<int EPI>
__device__ __forceinline__ void epi_store(float xa, int rr, int cc, int N,
                                          const float* __restrict__ bias,
                                          const void* __restrict__ aux,
                                          void* __restrict__ out, void* __restrict__ out2) {
  float x = xa + bias[cc];
  if (EPI == EPI_GATES) {
    if (cc < HID_) {
      x = tanhf(x);
      ((unsigned short*)out)[(size_t)rr * 2048 + (cc << 1)] = f2bf(x);
    } else if (cc < 2048) {
      ((unsigned short*)out)[(size_t)rr * 2048 + ((cc - 1024) << 1) + 1] = f2bf(x);
    } else {
      ((unsigned short*)out2)[(size_t)rr * 1024 + (cc - 2048)] = f2bf(x);
    }
  } else if (EPI == EPI_GELU) {
    x = 0.5f * x * (1.f + erff(x * 0.70710678118654752f));
    ((unsigned short*)out)[(size_t)rr * N + cc] = f2bf(x);
  } else if (EPI == EPI_RES) {
    x += ((const float*)aux)[(size_t)rr * N + cc];
    ((unsigned short*)out)[(size_t)rr * N + cc] = f2bf(x);
  } else if (EPI == EPI_HEAD) {
    x *= bf2f(((const unsigned short*)aux)[(size_t)rr * 1024 + cc]);
    ((float*)out)[(size_t)rr * N + cc] = x;
  } else {
    ((float*)out)[(size_t)rr * N + cc] = x;
  }
}

// ---------------- 128x128 m97-structure GEMM with strides + diag offset ----------------
template<int EPI, int DIAG>
__global__ __launch_bounds__(256)
void gemm_bt(const unsigned short* __restrict__ A, int lda,
             const unsigned short* __restrict__ Bt, int ldb,
             const float* __restrict__ bias, const void* __restrict__ aux,
             void* __restrict__ out, void* __restrict__ out2, int M, int N, int K) {
  __shared__ unsigned short lA[128 * 32];
  __shared__ unsigned short lB[128 * 32];
  const int tid = threadIdx.x;
  const int w = tid >> 6, l = tid & 63;
  // T1 XCD swizzle (nwg % 8 == 0)
  const int gx = gridDim.x, nwg = gx * gridDim.y;
  const int o = blockIdx.y * gx + blockIdx.x;
  const int lin = (o & 7) * (nwg >> 3) + (o >> 3);
  const int row0 = (lin / gx) * 128, col0 = (lin % gx) * 128;
  const int kOff = DIAG ? col0 : 0;

  const int rA0 = w * 16 + (l >> 2);
  const int rA1 = (4 + w) * 16 + (l >> 2);
  const int koff = (l & 3) * 8;
  const unsigned short* gA0 = A + (size_t)(row0 + rA0) * lda + kOff + koff;
  const unsigned short* gA1 = A + (size_t)(row0 + rA1) * lda + kOff + koff;
  const unsigned short* gB0 = Bt + (size_t)(col0 + rA0) * ldb + koff;
  const unsigned short* gB1 = Bt + (size_t)(col0 + rA1) * ldb + koff;
  unsigned short* lA0 = lA + w * 512;
  unsigned short* lA1 = lA + (4 + w) * 512;
  unsigned short* lB0 = lB + w * 512;
  unsigned short* lB1 = lB + (4 + w) * 512;

  const int wr = (w >> 1) * 64, wc = (w & 1) * 64;
  f32x4 acc[4][4];
  #pragma unroll
  for (int m = 0; m < 4; m++)
    #pragma unroll
    for (int n = 0; n < 4; n++) acc[m][n] = (f32x4){0.f, 0.f, 0.f, 0.f};

  const int arow = wr + (l & 15);
  const int brow = wc + (l & 15);
  const int kg = (l >> 4) * 8;

  for (int kt = 0; kt < K; kt += 32) {
    __syncthreads();
    gload16(gA0 + kt, lA0);
    gload16(gA1 + kt, lA1);
    gload16(gB0 + kt, lB0);
    gload16(gB1 + kt, lB1);
    __syncthreads();
    short8 af[4], bfr[4];
    #pragma unroll
    for (int m = 0; m < 4; m++) af[m]  = *(const short8*)(lA + (arow + m * 16) * 32 + kg);
    #pragma unroll
    for (int n = 0; n < 4; n++) bfr[n] = *(const short8*)(lB + (brow + n * 16) * 32 + kg);
    #pragma unroll
    for (int m = 0; m < 4; m++)
      #pragma unroll
      for (int n = 0; n < 4; n++)
        acc[m][n] = __builtin_amdgcn_mfma_f32_16x16x32_bf16(af[m], bfr[n], acc[m][n], 0, 0, 0);
  }

  const int er = row0 + wr + ((l >> 4) << 2);
  const int ec = col0 + wc + (l & 15);
  #pragma unroll
  for (int m = 0; m < 4; m++)
    #pragma unroll
    for (int n = 0; n < 4; n++)
      #pragma unroll
      for (int j = 0; j < 4; j++)
        epi_store<EPI>(acc[m][n][j], er + m * 16 + j, ec + n * 16, N, bias, aux, out, out2);
}

// ---------------- 256x256 8-phase GEMM (T1+T2+T3/T4+T5, distance-2 prefetch) ----------------
template<int EPI>
__global__ __launch_bounds__(512, 2)
void gemm256(const unsigned short* __restrict__ A, const unsigned short* __restrict__ Bt,
             const float* __restrict__ bias, const void* __restrict__ aux,
             void* __restrict__ out, void* __restrict__ out2, int M, int N, int K) {
  __shared__ unsigned short lds[2][2][256 * 64];
  const int tid = threadIdx.x;
  const int w = tid >> 6, l = tid & 63;
  const int wm = w >> 2, wn = w & 3;
  const int gx = gridDim.x, nwg = gx * gridDim.y;
  const int o = blockIdx.y * gx + blockIdx.x;
  const int lin = (o & 7) * (nwg >> 3) + (o >> 3);
  const int row0 = (lin / gx) * 256, col0 = (lin % gx) * 256;
  const int lr = l & 15, kg = (l >> 4) << 3;
  const int wmb = wm * 128, wnb = wn * 64;
  const int nIter = K >> 7;

  const int srow = w * 8 + (l >> 3);
  const int kswz = (((l & 7) ^ (l >> 3)) << 3);

  f32x4 acc[8][4];
  #pragma unroll
  for (int m = 0; m < 8; m++)
    #pragma unroll
    for (int n = 0; n < 4; n++) acc[m][n] = (f32x4){0.f, 0.f, 0.f, 0.f};

  short8 a[4][2], b0[2][2], b1[2][2];

  auto stA = [&](int buf, int hh, int kt) {   // one 128x64 half-tile = 2 loads
    const unsigned short* g = A + (size_t)(row0 + hh * 128 + srow) * K + kt * 64 + kswz;
    unsigned short* d = &lds[buf][0][hh * 8192 + w * 512];
    gload16(g, d);
    gload16(g + (size_t)64 * K, d + 4096);
  };
  auto stB = [&](int buf, int hh, int kt) {
    const unsigned short* g = Bt + (size_t)(col0 + hh * 128 + srow) * K + kt * 64 + kswz;
    unsigned short* d = &lds[buf][1][hh * 8192 + w * 512];
    gload16(g, d);
    gload16(g + (size_t)64 * K, d + 4096);
  };

#define RD_A(LP, mh) { _Pragma("unroll") for (int mf = 0; mf < 4; ++mf) { _Pragma("unroll") for (int ks = 0; ks < 2; ++ks) { \
      int r = wmb + (mh) * 64 + mf * 16 + lr; int k = ks * 32 + kg; \
      a[mf][ks] = *(const short8*)((LP) + r * 64 + (k ^ ((r & 7) << 3))); } } }
#define RD_B(dst, LP, nh) { _Pragma("unroll") for (int nf = 0; nf < 2; ++nf) { _Pragma("unroll") for (int ks = 0; ks < 2; ++ks) { \
      int r = wnb + (nh) * 32 + nf * 16 + lr; int k = ks * 32 + kg; \
      dst[nf][ks] = *(const short8*)((LP) + r * 64 + (k ^ ((r & 7) << 3))); } } }
#define MMA(bb, MB, NB) \
    __builtin_amdgcn_s_setprio(1); \
    _Pragma("unroll") for (int mf = 0; mf < 4; ++mf) { _Pragma("unroll") for (int nf = 0; nf < 2; ++nf) { _Pragma("unroll") for (int ks = 0; ks < 2; ++ks) { \
      acc[(MB) + mf][(NB) + nf] = __builtin_amdgcn_mfma_f32_16x16x32_bf16(a[mf][ks], bb[nf][ks], acc[(MB) + mf][(NB) + nf], 0, 0, 0); } } } \
    __builtin_amdgcn_s_setprio(0);
#define BAR __builtin_amdgcn_s_barrier()

  // prologue: tiles 0 and 1 fully staged; drain tile0 (leave tile1's 8 in flight)
  stA(0, 0, 0); stA(0, 1, 0); stB(0, 0, 0); stB(0, 1, 0);
  stA(1, 0, 1); stA(1, 1, 1); stB(1, 0, 1); stB(1, 1, 1);
  asm volatile("s_waitcnt vmcnt(8)" ::: "memory");
  BAR;

  for (int i = 0; i < nIter; ++i) {
    const int t2 = 2 * i + 2, t3 = 2 * i + 3;
    const bool pf = (i + 1 < nIter);
    const unsigned short* LA0 = lds[0][0];
    const unsigned short* LB0 = lds[0][1];
    const unsigned short* LA1 = lds[1][0];
    const unsigned short* LB1 = lds[1][1];

    // ---- tile 2i (buf0); stage tile 2i+2 -> buf0 per slot liveness ----
    RD_A(LA0, 0); RD_B(b0, LB0, 0);
    BAR; MMA(b0, 0, 0); BAR;
    RD_B(b1, LB0, 1);
    BAR; MMA(b1, 0, 2); BAR;                     // B slots of buf0 now dead
    RD_A(LA0, 1);
    if (pf) { stB(0, 0, t2); stB(0, 1, t2); }
    BAR; MMA(b0, 4, 0); BAR;                     // A slots of buf0 now dead
    if (pf) { stA(0, 0, t2); stA(0, 1, t2);
              asm volatile("s_waitcnt vmcnt(8)" ::: "memory"); }  // tile 2i+1 resident
    else    { asm volatile("s_waitcnt vmcnt(0)" ::: "memory"); }
    BAR; MMA(b1, 4, 2); BAR;

    // ---- tile 2i+1 (buf1); stage tile 2i+3 -> buf1 ----
    RD_A(LA1, 0); RD_B(b0, LB1, 0);
    BAR; MMA(b0, 0, 0); BAR;
    RD_B(b1, LB1, 1);
    BAR; MMA(b1, 0, 2); BAR;
    RD_A(LA1, 1);
    if (pf) { stB(1, 0, t3); stB(1, 1, t3); }
    BAR; MMA(b0, 4, 0); BAR;
    if (pf) { stA(1, 0, t3); stA(1, 1, t3);
              asm volatile("s_waitcnt vmcnt(8)" ::: "memory"); }  // tile 2i+2 resident
    BAR; MMA(b1, 4, 2); BAR;
  }
#undef RD_A
#undef RD_B
#undef MMA

  const int er = row0 + wmb + ((l >> 4) << 2);
  const int ec = col0 + wnb + lr;
  #pragma unroll
  for (int mi = 0; mi < 8; ++mi)
    #pragma unroll
    for (int ni = 0; ni < 4; ++ni)
      #pragma unroll
      for (int j = 0; j < 4; ++j)
        epi_store<EPI>(acc[mi][ni][j], er + mi * 16 + j, ec + ni * 16, N, bias, aux, out, out2);
}

// ---------------- 256x128 8-phase GEMM (distance-2 prefetch), for N%128 shapes ----------------
// waves: 4M x 2N, per-wave 64x64. LDS 96KB. 6 loads/tile -> steady vmcnt(6).
template<int EPI>
__global__ __launch_bounds__(512, 2)
void gemm256x128(const unsigned short* __restrict__ A, const unsigned short* __restrict__ Bt,
                 const float* __restrict__ bias, const void* __restrict__ aux,
                 void* __restrict__ out, void* __restrict__ out2, int M, int N, int K) {
  __shared__ unsigned short lA2[2][256 * 64];
  __shared__ unsigned short lB2[2][128 * 64];
  const int tid = threadIdx.x;
  const int w = tid >> 6, l = tid & 63;
  const int wm = w >> 1, wn = w & 1;
  const int gx = gridDim.x, nwg = gx * gridDim.y;
  const int o = blockIdx.y * gx + blockIdx.x;
  const int lin = (o & 7) * (nwg >> 3) + (o >> 3);
  const int row0 = (lin / gx) * 256, col0 = (lin % gx) * 128;
  const int lr = l & 15, kg = (l >> 4) << 3;
  const int nIter = K >> 7;

  const int srow = w * 8 + (l >> 3);
  const int kswz = (((l & 7) ^ (l >> 3)) << 3);

  f32x4 acc[4][4];
  #pragma unroll
  for (int m = 0; m < 4; m++)
    #pragma unroll
    for (int n = 0; n < 4; n++) acc[m][n] = (f32x4){0.f, 0.f, 0.f, 0.f};

  short8 a[2][2], b0[2][2], b1[2][2];

  auto stA = [&](int buf, int hh, int kt) {   // 128-row A half: 2 loads
    const unsigned short* g = A + (size_t)(row0 + hh * 128 + srow) * K + kt * 64 + kswz;
    unsigned short* d = &lA2[buf][hh * 8192 + w * 512];
    gload16(g, d);
    gload16(g + (size_t)64 * K, d + 4096);
  };
  auto stB = [&](int buf, int hh, int kt) {   // 64-row B half: 1 load
    const unsigned short* g = Bt + (size_t)(col0 + hh * 64 + srow) * K + kt * 64 + kswz;
    gload16(g, &lB2[buf][hh * 4096 + w * 512]);
  };

#define RDA2(buf, mh) { _Pragma("unroll") for (int mf = 0; mf < 2; ++mf) { _Pragma("unroll") for (int ks = 0; ks < 2; ++ks) { \
      int r = wm * 64 + (mh) * 32 + mf * 16 + lr; int k = ks * 32 + kg; \
      a[mf][ks] = *(const short8*)(&lA2[buf][r * 64 + (k ^ ((r & 7) << 3))]); } } }
#define RDB2(dst, buf, nh) { _Pragma("unroll") for (int nf = 0; nf < 2; ++nf) { _Pragma("unroll") for (int ks = 0; ks < 2; ++ks) { \
      int r = wn * 64 + (nh) * 32 + nf * 16 + lr; int k = ks * 32 + kg; \
      dst[nf][ks] = *(const short8*)(&lB2[buf][r * 64 + (k ^ ((r & 7) << 3))]); } } }
#define MMA2(bb, MB, NB) \
    __builtin_amdgcn_s_setprio(1); \
    _Pragma("unroll") for (int mf = 0; mf < 2; ++mf) { _Pragma("unroll") for (int nf = 0; nf < 2; ++nf) { _Pragma("unroll") for (int ks = 0; ks < 2; ++ks) { \
      acc[(MB) + mf][(NB) + nf] = __builtin_amdgcn_mfma_f32_16x16x32_bf16(a[mf][ks], bb[nf][ks], acc[(MB) + mf][(NB) + nf], 0, 0, 0); } } } \
    __builtin_amdgcn_s_setprio(0);
#define BAR2 __builtin_amdgcn_s_barrier()

  // prologue: tiles 0,1 fully staged (6 loads each); drain tile0
  stA(0, 0, 0); stA(0, 1, 0); stB(0, 0, 0); stB(0, 1, 0);
  stA(1, 0, 1); stA(1, 1, 1); stB(1, 0, 1); stB(1, 1, 1);
  asm volatile("s_waitcnt vmcnt(6)" ::: "memory");
  BAR2;

  for (int i = 0; i < nIter; ++i) {
    const int t2 = 2 * i + 2, t3 = 2 * i + 3;
    const bool pf = (i + 1 < nIter);

    // ---- tile 2i (buf0); stage 2i+2 -> buf0 ----
    RDA2(0, 0); RDB2(b0, 0, 0);
    BAR2; MMA2(b0, 0, 0); BAR2;
    RDB2(b1, 0, 1);
    BAR2; MMA2(b1, 0, 2); BAR2;                  // B slots dead
    RDA2(0, 1);
    if (pf) { stB(0, 0, t2); stB(0, 1, t2); }
    BAR2; MMA2(b0, 2, 0); BAR2;                  // A slots dead
    if (pf) { stA(0, 0, t2); stA(0, 1, t2);
              asm volatile("s_waitcnt vmcnt(6)" ::: "memory"); }
    else    { asm volatile("s_waitcnt vmcnt(0)" ::: "memory"); }
    BAR2; MMA2(b1, 2, 2); BAR2;

    // ---- tile 2i+1 (buf1); stage 2i+3 -> buf1 ----
    RDA2(1, 0); RDB2(b0, 1, 0);
    BAR2; MMA2(b0, 0, 0); BAR2;
    RDB2(b1, 1, 1);
    BAR2; MMA2(b1, 0, 2); BAR2;
    RDA2(1, 1);
    if (pf) { stB(1, 0, t3); stB(1, 1, t3); }
    BAR2; MMA2(b0, 2, 0); BAR2;
    if (pf) { stA(1, 0, t3); stA(1, 1, t3);
              asm volatile("s_waitcnt vmcnt(6)" ::: "memory"); }
    BAR2; MMA2(b1, 2, 2); BAR2;
  }
#undef RDA2
#undef RDB2
#undef MMA2

  const int er = row0 + wm * 64 + ((l >> 4) << 2);
  const int ec = col0 + wn * 64 + lr;
  #pragma unroll
  for (int mi = 0; mi < 4; ++mi)
    #pragma unroll
    for (int ni = 0; ni < 4; ++ni)
      #pragma unroll
      for (int j = 0; j < 4; ++j)
        epi_store<EPI>(acc[mi][ni][j], er + mi * 16 + j, ec + ni * 16, N, bias, aux, out, out2);
}

// ---------------- chunked affine scan (bf16 inputs, f32 accum) ----------------
__global__ void scan_p1(const unsigned short* __restrict__ ab16, float* __restrict__ aggA, float* __restrict__ aggB) {
  int id = blockIdx.x * 256 + threadIdx.x;
  int c = id & 1023;
  int chunk = (id >> 10) & (NCH - 1);
  int bb = id >> 14;
  const unsigned short* base = ab16 + (size_t)(bb * L_ + chunk * CLEN) * 2048 + 2 * c;
  float Aa = 1.f, Bv = 0.f;
  #pragma unroll 4
  for (int t = 0; t < CLEN; ++t) {
    unsigned int v = *(const unsigned int*)(base + (size_t)t * 2048);
    float a = bf2f(v & 0xffffu);
    float b = bf2f(v >> 16);
    Aa *= a;
    Bv = a * Bv + b;
  }
  int o = (chunk * B_ + bb) * 1024 + c;
  aggA[o] = Aa; aggB[o] = Bv;
}

__global__ void scan_p2(const float* __restrict__ aggA, const float* __restrict__ aggB,
                        float* __restrict__ hinit) {
  int id = blockIdx.x * 256 + threadIdx.x;
  float hc = 0.f;
  for (int ch = 0; ch < NCH; ++ch) {
    int o = ch * 4096 + id;
    hinit[o] = hc;
    hc = aggA[o] * hc + aggB[o];
  }
}

__global__ void scan_p3(const unsigned short* __restrict__ ab16, const float* __restrict__ hinit,
                        unsigned short* __restrict__ hb16) {
  int id = blockIdx.x * 256 + threadIdx.x;
  int c = id & 1023;
  int chunk = (id >> 10) & (NCH - 1);
  int bb = id >> 14;
  const unsigned short* base = ab16 + (size_t)(bb * L_ + chunk * CLEN) * 2048 + 2 * c;
  unsigned short* hb = hb16 + (size_t)(bb * L_ + chunk * CLEN) * 1024;
  float h = hinit[chunk * 4096 + bb * 1024 + c];
  #pragma unroll 4
  for (int t = 0; t < CLEN; ++t) {
    unsigned int v = *(const unsigned int*)(base + (size_t)t * 2048);
    float a = bf2f(v & 0xffffu);
    float b = bf2f(v >> 16);
    h = a * h + b;
    hb[(size_t)t * 1024 + c] = f2bf(h);
  }
}

// ---------------- u = z + LN(z); outputs f32 + bf16 ----------------
__global__ __launch_bounds__(256)
void ln_res(const float* __restrict__ z, const float* __restrict__ lg, const float* __restrict__ lb,
            float* __restrict__ u32, unsigned short* __restrict__ u16) {
  int row = blockIdx.x;
  int t = threadIdx.x;
  const float4 zv = *(const float4*)(z + (size_t)row * 1024 + t * 4);
  float s = zv.x + zv.y + zv.z + zv.w;
  float sq = zv.x * zv.x + zv.y * zv.y + zv.z * zv.z + zv.w * zv.w;
  #pragma unroll
  for (int o = 32; o > 0; o >>= 1) { s += __shfl_down(s, o); sq += __shfl_down(sq, o); }
  __shared__ float ps[4], pq[4];
  if ((t & 63) == 0) { ps[t >> 6] = s; pq[t >> 6] = sq; }
  __syncthreads();
  s = ps[0] + ps[1] + ps[2] + ps[3];
  sq = pq[0] + pq[1] + pq[2] + pq[3];
  float mu = s * (1.f / 1024.f);
  float var = sq * (1.f / 1024.f) - mu * mu;
  float rs = rsqrtf(var + 1e-5f);
  const float4 gv = *(const float4*)(lg + t * 4);
  const float4 bv = *(const float4*)(lb + t * 4);
  float4 o;
  o.x = zv.x + (zv.x - mu) * rs * gv.x + bv.x;
  o.y = zv.y + (zv.y - mu) * rs * gv.y + bv.y;
  o.z = zv.z + (zv.z - mu) * rs * gv.z + bv.z;
  o.w = zv.w + (zv.w - mu) * rs * gv.w + bv.w;
  *(float4*)(u32 + (size_t)row * 1024 + t * 4) = o;
  ushort4 ob; ob.x = f2bf(o.x); ob.y = f2bf(o.y); ob.z = f2bf(o.z); ob.w = f2bf(o.w);
  *(ushort4*)(u16 + (size_t)row * 1024 + t * 4) = ob;
}

extern "C" void kernel_launch(void* const* d_in, const int* in_sizes, int n_in,
                              void* d_out, int out_size, void* d_ws, size_t ws_size,
                              hipStream_t stream) {
  const float* emb    = (const float*)d_in[0];
  const float* Wa     = (const float*)d_in[1];
  const float* ba     = (const float*)d_in[2];
  const float* Wb     = (const float*)d_in[3];
  const float* bb     = (const float*)d_in[4];
  const float* WD     = (const float*)d_in[5];
  const float* bD     = (const float*)d_in[6];
  const float* WC     = (const float*)d_in[7];
  const float* bC     = (const float*)d_in[8];
  const float* ffn1_w = (const float*)d_in[9];
  const float* ffn1_b = (const float*)d_in[10];
  const float* ffn2_w = (const float*)d_in[11];
  const float* ffn2_b = (const float*)d_in[12];
  const float* proj_w = (const float*)d_in[13];
  const float* proj_b = (const float*)d_in[14];
  const float* ln_g   = (const float*)d_in[15];
  const float* ln_b   = (const float*)d_in[16];

  char* p = (char*)d_ws;
  auto alloc = [&](size_t bytes) { char* r = p; p += (bytes + 255) & ~(size_t)255; return (void*)r; };

  unsigned short* ab16 = (unsigned short*)alloc((size_t)ROWS * 2048 * 2);  // 32MB (a,b) pairs
  unsigned short* d16  = (unsigned short*)alloc((size_t)ROWS * 1024 * 2);  // 16MB d gate
  unsigned short* hb16 = (unsigned short*)alloc((size_t)ROWS * 1024 * 2);  // 16MB scan h
  float* zbuf  = (float*)alloc((size_t)ROWS * 1024 * 4);                   // 32MB
  float* u32   = (float*)alloc((size_t)ROWS * 1024 * 4);
  unsigned short* u16  = (unsigned short*)alloc((size_t)ROWS * 1024 * 2);
  unsigned short* embb = (unsigned short*)alloc((size_t)ROWS * 1024 * 2);
  unsigned short* wcat = (unsigned short*)alloc((size_t)3072 * 1024 * 2);
  unsigned short* f1t  = (unsigned short*)alloc((size_t)4096 * 1024 * 2);
  unsigned short* f2t  = (unsigned short*)alloc((size_t)4096 * 1024 * 2);
  unsigned short* pjt  = (unsigned short*)alloc((size_t)1024 * 1024 * 2);
  unsigned short* wcd  = (unsigned short*)alloc((size_t)1024 * 128 * 2);
  float* biascat = (float*)alloc(3072 * 4);
  float* aggA  = (float*)alloc(65536 * 4);
  float* aggB  = (float*)alloc(65536 * 4);
  float* hinit = (float*)alloc(65536 * 4);
  // aliases (disjoint lifetimes):
  unsigned short* gbuf = ab16;                  // [ROWS][4096] bf16, written by FFN1 (after head)
  unsigned short* vbuf = (unsigned short*)zbuf; // [ROWS][1024] bf16, written by FFN2 (after ln_res)

  dim3 tb(32, 8);
  cast_f32_bf16<<<ROWS * 1024 / 1024, 256, 0, stream>>>(emb, embb, ROWS * 1024);
  build_bias<<<12, 256, 0, stream>>>(ba, bb, bD, biascat);
  build_wcd<<<1024 * 128 / 256, 256, 0, stream>>>(WC, wcd);
  transpose_cast<<<dim3(E_ / 32, DH_ / 32, H_), tb, 0, stream>>>(Wa, wcat, E_, DH_, 0);
  transpose_cast<<<dim3(E_ / 32, DH_ / 32, H_), tb, 0, stream>>>(Wb, wcat, E_, DH_, 1024);
  transpose_cast<<<dim3(E_ / 32, DH_ / 32, H_), tb, 0, stream>>>(WD, wcat, E_, DH_, 2048);
  transpose_cast<<<dim3(1024 / 32, 4096 / 32, 1), tb, 0, stream>>>(ffn1_w, f1t, 1024, 4096, 0);
  transpose_cast<<<dim3(4096 / 32, 1024 / 32, 1), tb, 0, stream>>>(ffn2_w, f2t, 4096, 1024, 0);
  transpose_cast<<<dim3(1024 / 32, 1024 / 32, 1), tb, 0, stream>>>(proj_w, pjt, 1024, 1024, 0);

  // G1: [8192,1024]x[1024,3072] -> ab16 + d16   [256x128 8-phase, 768 wg = 3 exact rounds]
  gemm256x128<EPI_GATES><<<dim3(3072 / 128, ROWS / 256), 512, 0, stream>>>(
      embb, wcat, biascat, nullptr, ab16, d16, ROWS, 3072, 1024);

  scan_p1<<<65536 / 256, 256, 0, stream>>>(ab16, aggA, aggB);
  scan_p2<<<4096 / 256, 256, 0, stream>>>(aggA, aggB, hinit);
  scan_p3<<<65536 / 256, 256, 0, stream>>>(ab16, hinit, hb16);

  // head: z = (h @ WC_diag + bC) * d ; K=128 diag window per col-block
  gemm_bt<EPI_HEAD, 1><<<dim3(1024 / 128, ROWS / 128), 256, 0, stream>>>(
      hb16, 1024, wcd, 128, bC, d16, zbuf, nullptr, ROWS, 1024, 128);

  ln_res<<<ROWS, 256, 0, stream>>>(zbuf, ln_g, ln_b, u32, u16);

  // FFN1: [8192,1024]x[1024,4096] -> gelu -> gbuf   [256^2 8-phase, 512 wg = 2 rounds]
  gemm256<EPI_GELU><<<dim3(4096 / 256, ROWS / 256), 512, 0, stream>>>(
      u16, f1t, ffn1_b, nullptr, gbuf, nullptr, ROWS, 4096, 1024);
  // FFN2: [8192,4096]x[4096,1024] + u -> vbuf       [256x128 8-phase, 256 wg]
  gemm256x128<EPI_RES><<<dim3(1024 / 128, ROWS / 256), 512, 0, stream>>>(
      gbuf, f2t, ffn2_b, u32, vbuf, nullptr, ROWS, 1024, 4096);
  // proj: [8192,1024]x[1024,1024] -> d_out (f32)    [256x128 8-phase, 256 wg]
  gemm256x128<EPI_OUT><<<dim3(1024 / 128, ROWS / 256), 512, 0, stream>>>(
      vbuf, pjt, proj_b, nullptr, (float*)d_out, nullptr, ROWS, 1024, 1024);
}